// Round 5
// baseline (287.544 us; speedup 1.0000x reference)
//
#include <hip/hip_runtime.h>
#include <cstdint>
#include <cstddef>

// B=8, N=2048, C=512
// out = feature + softmax(Q K^T) @ V / sqrt(C),  Q = X Wq^T + bq etc.
// R15: operand-residency restructure.
//  - gemm_qk9: A(keys)-resident GEMM. K-rows [128][512] live in LDS for the
//    whole block (loaded once); only 16KB Q-tiles stream (dbuf, 1-ahead,
//    reads AFTER VMW(2)+SBAR -- FIFO: phase p enters with tile p's 2 loads
//    outstanding, stages tile p+1, VMW(2) completes tile p). 64 phases,
//    grid 256 (1 block/CU, z==XCD), 8 waves 2x4, per-wave 64x64.
//    LDS = 128K (A) + 2x16K (B) = 160 KiB exactly.
//  - gemm_pv9: P-read-once (d-split=1 -> P fetched 1x, was 4x) + V-frags
//    DIRECT global->reg (no LDS, per-wave private, 1-ahead in registers).
//    P through a 3-slot LDS ring, 2-ahead, VMW(9)/(8)/(0) enumerated.
//    Block = 64 q x 512 d, 32 phases, grid 256.
// prep / gemm_qkv unchanged.

typedef __bf16 bf16x8 __attribute__((ext_vector_type(8)));
typedef float f32x4 __attribute__((ext_vector_type(4)));
typedef short short4v __attribute__((ext_vector_type(4)));

__device__ __forceinline__ short f2b(float f) {
  union { float f; unsigned u; } u; u.f = f;
  unsigned r = (u.u + 0x7fffu + ((u.u >> 16) & 1u)) >> 16;  // RNE
  return (short)r;
}

#define GLDS(gptr, lptr) \
  __builtin_amdgcn_global_load_lds( \
      (const __attribute__((address_space(1))) unsigned int*)(const void*)(gptr), \
      (__attribute__((address_space(3))) unsigned int*)(void*)(lptr), 16, 0, 0)

// plain fragment load from [rows][64] XOR-swizzled LDS (gemm_qkv only).
__device__ __forceinline__ bf16x8 ldfrag64(const short* buf, int row, int kq) {
  return *(const bf16x8*)(buf + row * 64 + ((kq ^ (row & 7)) * 8));
}

// asm ds_read_b128 (invisible to SIInsertWaitcnts; completion guaranteed
// only by the explicit lgkmcnt(0) that follows).
__device__ __forceinline__ bf16x8 ds_asm(const short* p) {
  bf16x8 r;
  asm volatile("ds_read_b128 %0, %1"
               : "=v"(r)
               : "v"((const __attribute__((address_space(3))) short*)(const void*)p));
  return r;
}
// [rows][512] resident A buffer: chunk c in 0..63, swizzle c^(r&7) -> 2-way banks.
__device__ __forceinline__ bf16x8 ldfragA(const short* buf, int row, int c) {
  return ds_asm(buf + row * 512 + ((c ^ (row & 7)) * 8));
}
// [rows][32] streamed B buffer: chunk l4 in 0..3, swizzle l4^((r>>1)&3) -> 2-way.
__device__ __forceinline__ bf16x8 ldfrag32(const short* buf, int row, int l4) {
  return ds_asm(buf + row * 32 + ((l4 ^ ((row >> 1) & 3)) * 8));
}
// [64][64] P tile: chunk c in 0..7, swizzle c^(r&7) -> 2-way.
__device__ __forceinline__ bf16x8 ldfragP(const short* buf, int row, int c) {
  return ds_asm(buf + row * 64 + ((c ^ (row & 7)) * 8));
}

#define LGKM0_SB() do { \
    asm volatile("s_waitcnt lgkmcnt(0)" ::: "memory"); \
    __builtin_amdgcn_sched_barrier(0); } while (0)
#define VMW(n) asm volatile("s_waitcnt vmcnt(" #n ")" ::: "memory")
#define SBAR() __builtin_amdgcn_s_barrier()
#define PRIO1() __builtin_amdgcn_s_setprio(1)
#define PRIO0() __builtin_amdgcn_s_setprio(0)

// ---------------- merged prep: feature->bf16, weights->bf16, bias pack, l=0 ----------------
__global__ __launch_bounds__(256) void prep(const float* __restrict__ f,
                                            const float* __restrict__ w0,
                                            const float* __restrict__ w1,
                                            const float* __restrict__ w2,
                                            const float* __restrict__ b0,
                                            const float* __restrict__ b1,
                                            const float* __restrict__ b2,
                                            short* __restrict__ Xb, short* __restrict__ Wb,
                                            float* __restrict__ biasP, float* __restrict__ l) {
  const int bid = blockIdx.x;
  const int t = threadIdx.x;
  if (bid < 8192) {                       // feature: 2097152 float4
    int i = bid * 256 + t;
    float4 v = ((const float4*)f)[i];
    short4v o = { f2b(v.x), f2b(v.y), f2b(v.z), f2b(v.w) };
    *(short4v*)(Xb + (size_t)i * 4) = o;
  } else if (bid < 8960) {                // weights: 196608 float4
    int i = (bid - 8192) * 256 + t;
    const float* src = (i < 65536) ? w0 : (i < 131072) ? w1 : w2;
    float4 v = ((const float4*)src)[i & 65535];
    short4v o = { f2b(v.x), f2b(v.y), f2b(v.z), f2b(v.w) };
    *(short4v*)(Wb + (size_t)i * 4) = o;
  } else {                                // 8 blocks: l zero (16384 f32) + bias (1536)
    int i = (bid - 8960) * 256 + t;       // 0..2047
    float4 z = { 0.f, 0.f, 0.f, 0.f };
    ((float4*)l)[i * 2] = z;
    ((float4*)l)[i * 2 + 1] = z;
    if (i < 1536) {
      const float* s = (i < 512) ? b0 : (i < 1024) ? b1 : b2;
      biasP[i] = s[i & 511];
    }
  }
}

// ---------------- fused QKV projection: 128x128 tile, BK=64 swizzled, 16x16x32 ----------------
__global__ __launch_bounds__(256) void gemm_qkv(const short* __restrict__ X,
                                                const short* __restrict__ Wall,
                                                const float* __restrict__ biasP,
                                                short* __restrict__ Out,
                                                short* __restrict__ VtOut) {
  __shared__ __align__(16) short Xs[128 * 64];
  __shared__ __align__(16) short Ws[128 * 64];
  const int z = blockIdx.z;
  const short* Wm = Wall + (size_t)z * 262144;
  const int m0 = blockIdx.y * 128, n0 = blockIdx.x * 128;
  const int t = threadIdx.x;
  const int lane = t & 63, w = t >> 6;
  const int wn = (w & 1) * 64, wm = (w >> 1) * 64;
  const int fr = lane & 15, l4 = lane >> 4;

  f32x4 acc[4][4] = {};

  for (int k0 = 0; k0 < 512; k0 += 64) {
    __syncthreads();
#pragma unroll
    for (int u = 0; u < 4; ++u) {
      int cc = t + u * 256;
      int r = cc >> 3, cs = cc & 7;
      int kk = ((cs ^ (r & 7)) * 8);
      GLDS(X + (size_t)(m0 + r) * 512 + k0 + kk, Xs + cc * 8);
      GLDS(Wm + (size_t)(n0 + r) * 512 + k0 + kk, Ws + cc * 8);
    }
    __syncthreads();
#pragma unroll
    for (int h = 0; h < 2; ++h) {
      bf16x8 wf[4], xf[4];
#pragma unroll
      for (int i = 0; i < 4; ++i) wf[i] = ldfrag64(Ws, wn + i * 16 + fr, h * 4 + l4);
#pragma unroll
      for (int j = 0; j < 4; ++j) xf[j] = ldfrag64(Xs, wm + j * 16 + fr, h * 4 + l4);
      if (z < 2) {
#pragma unroll
        for (int i = 0; i < 4; ++i)
#pragma unroll
          for (int j = 0; j < 4; ++j)
            acc[i][j] = __builtin_amdgcn_mfma_f32_16x16x32_bf16(wf[i], xf[j], acc[i][j], 0, 0, 0);
      } else {
#pragma unroll
        for (int i = 0; i < 4; ++i)
#pragma unroll
          for (int j = 0; j < 4; ++j)
            acc[i][j] = __builtin_amdgcn_mfma_f32_16x16x32_bf16(xf[i], wf[j], acc[i][j], 0, 0, 0);
      }
    }
  }

  const int rq = l4 * 4;
  if (z < 2) {
#pragma unroll
    for (int i = 0; i < 4; ++i) {
      int nb = n0 + wn + i * 16 + rq;
      float4 bs = *(const float4*)(biasP + z * 512 + nb);
#pragma unroll
      for (int j = 0; j < 4; ++j) {
        int m = m0 + wm + j * 16 + fr;
        short4v o = { f2b(acc[i][j][0] + bs.x), f2b(acc[i][j][1] + bs.y),
                      f2b(acc[i][j][2] + bs.z), f2b(acc[i][j][3] + bs.w) };
        *(short4v*)(Out + (size_t)z * 8388608 + (size_t)m * 512 + nb) = o;
      }
    }
  } else {
    const int zB = blockIdx.y >> 4;
    const int mb = m0 & 2047;
#pragma unroll
    for (int j = 0; j < 4; ++j) {
      int d = n0 + wn + j * 16 + fr;
      float bd = biasP[1024 + d];
#pragma unroll
      for (int i = 0; i < 4; ++i) {
        int mloc = mb + wm + i * 16 + rq;
        short4v o = { f2b(acc[i][j][0] + bd), f2b(acc[i][j][1] + bd),
                      f2b(acc[i][j][2] + bd), f2b(acc[i][j][3] + bd) };
        *(short4v*)(VtOut + (size_t)zB * 1048576 + (size_t)d * 2048 + mloc) = o;
      }
    }
  }
}

// ---------------- QK^T: A(keys)-resident, 128 keys x 1024 q per block ----------------
// A = K[128 rows][512] resident in LDS (128 KB). B = Q tiles [256][32] dbuf.
// 8 waves 2(keys)x4(q), per-wave 64x64. 4 q-tiles x 16 K-tiles = 64 phases.
// Phase p (= qt*16+kt): stage tile p+1 -> buf[c^1]; VMW(2) [tile p done];
// SBAR; 8 asm ds_reads; lgkm0; 16 MFMA; SBAR. Epilogue per q-tile.
__global__ __launch_bounds__(512) void gemm_qk9(const short* __restrict__ Q,
                                                const short* __restrict__ Kb,
                                                short* __restrict__ P,
                                                float* __restrict__ l) {
  __shared__ __align__(16) short As[128 * 512];   // 128 KB, chunk swizzle c^(r&7)
  __shared__ __align__(16) short Bs[2][256 * 32]; // 2 x 16 KB
  const int id = blockIdx.x;       // 256 blocks, z == XCD (id%8)
  const int z = id & 7;
  const int kb = (id >> 3) & 15;
  const int qh = id >> 7;          // 0..1
  const int m0 = kb * 128;
  const short* __restrict__ Ag = Kb + (size_t)z * 1048576 + (size_t)m0 * 512;
  const short* __restrict__ Bg = Q + (size_t)z * 1048576 + (size_t)(qh * 1024) * 512;
  const int t = threadIdx.x;
  const int lane = t & 63, w = t >> 6;
  const int aw = (w >> 2) * 64, bw = (w & 3) * 64;
  const int fr = lane & 15, l4 = lane >> 4;
  // B staging: rows br and br+128, same chunk col bc; source pre-swizzled.
  const int br = t >> 2, bc = t & 3;
  const int bcs1 = (bc ^ ((br >> 1) & 3)) * 8;
  const int bcs2 = (bc ^ (((br + 128) >> 1) & 3)) * 8;

#define QK_STG_B(buf, qt, kt) do { \
    GLDS(Bg + (size_t)((qt) * 256 + br) * 512 + (kt) * 32 + bcs1, &Bs[(buf)][t * 8]); \
    GLDS(Bg + (size_t)((qt) * 256 + br + 128) * 512 + (kt) * 32 + bcs2, \
         &Bs[(buf)][4096 + t * 8]); \
  } while (0)

  // ---- prologue: A resident (16 chunks/thread, linear dest, pre-swizzled src) + tile 0
#pragma unroll
  for (int j = 0; j < 16; ++j) {
    int Lc = t + j * 512;                 // 0..8191
    int r = Lc >> 6, c = Lc & 63;
    GLDS(Ag + (size_t)r * 512 + (c ^ (r & 7)) * 8, As + Lc * 8);
  }
  QK_STG_B(0, 0, 0);
  VMW(0);
  SBAR();

  f32x4 acc[4][4] = {};
  const float LOG2E = 1.4426950408889634f;

  for (int qt = 0; qt < 4; ++qt) {
#pragma unroll 1
    for (int kt = 0; kt < 16; ++kt) {
      const int p = qt * 16 + kt;
      const int c = kt & 1;
      if (p < 63) {
        const int pn = p + 1;
        QK_STG_B(c ^ 1, pn >> 4, pn & 15);
        VMW(2);      // tile p complete (entering outstanding = tile p's 2)
      } else {
        VMW(0);
      }
      SBAR();
      bf16x8 af[4], bf[4];
#pragma unroll
      for (int i = 0; i < 4; ++i) af[i] = ldfragA(As, aw + i * 16 + fr, kt * 4 + l4);
#pragma unroll
      for (int n = 0; n < 4; ++n) bf[n] = ldfrag32(&Bs[c][0], bw + n * 16 + fr, l4);
      LGKM0_SB(); PRIO1();
#pragma unroll
      for (int i = 0; i < 4; ++i)
#pragma unroll
        for (int n = 0; n < 4; ++n)
          acc[i][n] = __builtin_amdgcn_mfma_f32_16x16x32_bf16(af[i], bf[n], acc[i][n], 0, 0, 0);
      PRIO0(); SBAR();
    }
    // ---- per-q-tile epilogue: exp, store P[q][key], row-sum atomics, acc reset.
    const int qbase = qh * 1024 + qt * 256;
    float rs[4] = { 0.f, 0.f, 0.f, 0.f };
#pragma unroll
    for (int i = 0; i < 4; ++i) {
      const int key = m0 + aw + i * 16 + l4 * 4;
#pragma unroll
      for (int n = 0; n < 4; ++n) {
        const int q = qbase + bw + n * 16 + fr;
        short4v o;
        float part = 0.f;
#pragma unroll
        for (int r = 0; r < 4; ++r) {
          float e = exp2f(acc[i][n][r] * LOG2E);
          o[r] = f2b(e);
          part += e;
        }
        *(short4v*)(P + (size_t)z * 4194304 + (size_t)q * 2048 + key) = o;
        rs[n] += part;
        acc[i][n] = (f32x4){ 0.f, 0.f, 0.f, 0.f };
      }
    }
#pragma unroll
    for (int n = 0; n < 4; ++n) {
      rs[n] += __shfl_xor(rs[n], 16);
      rs[n] += __shfl_xor(rs[n], 32);
    }
    if (l4 == 0) {
#pragma unroll
      for (int n = 0; n < 4; ++n)
        atomicAdd(&l[z * 2048 + qbase + bw + n * 16 + fr], rs[n]);
    }
  }
#undef QK_STG_B
}

// ---------------- PV: 64 q x 512 d per block; P read ONCE; V direct to regs ----------------
// A = Vt d-rows (global->reg, per-wave private, 1-ahead); B = P q-rows via
// 3-slot LDS ring (2-ahead). 8 waves, wave w owns d in [w*64, w*64+64).
// Per phase: issue vt(kt+1) (8 plain loads) + P(kt+2) GLDS (1/thread);
// 8 asm ds_reads of P(kt); VMW(9) [drains vt(kt)+P(kt+1)]; SBAR; lgkm0;
// 32 MFMA; SBAR. Tails: kt=30 VMW(8), kt=31 VMW(0). FIFO invariant: after
// phase kt's VMW(9), outstanding = [vt(kt+1) 8, P(kt+2) 1].
__global__ __launch_bounds__(512) void gemm_pv9(const short* __restrict__ Pm,
                                                const short* __restrict__ Vt,
                                                const float* __restrict__ l,
                                                const float* __restrict__ resid,
                                                float* __restrict__ out, float scale) {
  __shared__ __align__(16) short Ps[3][64 * 64];   // 3 x 8 KB ring
  const int id = blockIdx.x;       // 256 blocks, z == XCD
  const int z = id & 7;
  const int q0 = (id >> 3) * 64;
  const short* __restrict__ Pg = Pm + (size_t)z * 4194304 + (size_t)q0 * 2048;
  const short* __restrict__ Vg = Vt + (size_t)z * 1048576;
  const int t = threadIdx.x;
  const int lane = t & 63, w = t >> 6;
  const int dw = w * 64;
  const int fr = lane & 15, l4 = lane >> 4;
  // P staging: 512 chunks, 1/thread, linear dest, pre-swizzled source.
  const int pr = t >> 3, pc = t & 7;
  const int pcs = (pc ^ (pr & 7)) * 8;

#define PV_STG_P(s, kt) GLDS(Pg + (size_t)pr * 2048 + (kt) * 64 + pcs, &Ps[(s)][t * 8])

  // Vt fragment base: lane reads rows dw + i*16 + fr, k-chunk l4 within slice.
  const short* vbase = Vg + (size_t)(dw + fr) * 2048 + l4 * 8;

  f32x4 acc[4][4] = {};
  bf16x8 vc[4][2], vn[4][2];

  // ---- prologue: P(0), P(1) staged; vt(0) loaded; drain all.
  PV_STG_P(0, 0);
  PV_STG_P(1, 1);
#pragma unroll
  for (int i = 0; i < 4; ++i)
#pragma unroll
    for (int kk = 0; kk < 2; ++kk)
      vc[i][kk] = *(const bf16x8*)(vbase + (size_t)i * 16 * 2048 + kk * 32);
  VMW(0);
  SBAR();

#pragma unroll 1
  for (int kt = 0; kt < 32; ++kt) {
    if (kt < 31) {
#pragma unroll
      for (int i = 0; i < 4; ++i)
#pragma unroll
        for (int kk = 0; kk < 2; ++kk)
          vn[i][kk] = *(const bf16x8*)(vbase + (size_t)i * 16 * 2048 +
                                       (size_t)(kt + 1) * 64 + kk * 32);
    }
    if (kt < 30) PV_STG_P((kt + 2) % 3, kt + 2);
    bf16x8 pf[4][2];
    {
      const short* Pc = &Ps[kt % 3][0];
#pragma unroll
      for (int n = 0; n < 4; ++n)
#pragma unroll
        for (int kk = 0; kk < 2; ++kk)
          pf[n][kk] = ldfragP(Pc, n * 16 + fr, kk * 4 + l4);
    }
    if (kt < 30) { VMW(9); } else if (kt == 30) { VMW(8); } else { VMW(0); }
    SBAR();
    LGKM0_SB(); PRIO1();
#pragma unroll
    for (int kk = 0; kk < 2; ++kk)
#pragma unroll
      for (int i = 0; i < 4; ++i)
#pragma unroll
        for (int n = 0; n < 4; ++n)
          acc[i][n] = __builtin_amdgcn_mfma_f32_16x16x32_bf16(vc[i][kk], pf[n][kk],
                                                              acc[i][n], 0, 0, 0);
    PRIO0(); SBAR();
    if (kt < 31) {
#pragma unroll
      for (int i = 0; i < 4; ++i)
#pragma unroll
        for (int kk = 0; kk < 2; ++kk) vc[i][kk] = vn[i][kk];
    }
  }
#undef PV_STG_P

  // ---- epilogue: out = resid + acc * (scale / l[q])
  float linv[4];
#pragma unroll
  for (int n = 0; n < 4; ++n)
    linv[n] = scale / l[z * 2048 + q0 + n * 16 + fr];
#pragma unroll
  for (int n = 0; n < 4; ++n) {
    const int q = q0 + n * 16 + fr;
#pragma unroll
    for (int i = 0; i < 4; ++i) {
      const int d = dw + i * 16 + l4 * 4;
      const size_t idx = (size_t)z * 1048576 + (size_t)q * 512 + d;
      float4 rv = *(const float4*)(resid + idx);
      float4 o = { rv.x + acc[i][n][0] * linv[n], rv.y + acc[i][n][1] * linv[n],
                   rv.z + acc[i][n][2] * linv[n], rv.w + acc[i][n][3] * linv[n] };
      *(float4*)(out + idx) = o;
    }
  }
}

extern "C" void kernel_launch(void* const* d_in, const int* in_sizes, int n_in,
                              void* d_out, int out_size, void* d_ws, size_t ws_size,
                              hipStream_t stream) {
  const float* feature = (const float*)d_in[0];
  const float* wq = (const float*)d_in[1];
  const float* bq = (const float*)d_in[2];
  const float* wk = (const float*)d_in[3];
  const float* bk = (const float*)d_in[4];
  const float* wv = (const float*)d_in[5];
  const float* bv = (const float*)d_in[6];
  float* out = (float*)d_out;

  const size_t MN = (size_t)16384 * 512;
  short* Xb = (short*)d_ws;       // MN
  short* Wb = Xb + MN;            // 3 * 262144
  short* Q = Wb + 786432;         // MN (K follows contiguously)
  short* K = Q + MN;
  short* Vt = K + MN;             // [8][512][2048]
  short* P = Vt + MN;             // [8][2048][2048] unnormalized exp
  float* biasP = (float*)(P + (size_t)8 * 2048 * 2048);  // [3][512]
  float* l = biasP + 1536;        // [8*2048] row sums of exp

  prep<<<8968, 256, 0, stream>>>(feature, wq, wk, wv, bq, bk, bv, Xb, Wb, biasP, l);

  gemm_qkv<<<dim3(4, 128, 3), 256, 0, stream>>>(Xb, Wb, biasP, Q, Vt);
  gemm_qk9<<<256, 512, 0, stream>>>(Q, K, P, l);

  const float iscl = 0.044194173824159216f;  // 1/sqrt(512)
  gemm_pv9<<<256, 512, 0, stream>>>(P, Vt, l, feature, out, iscl);
}

// Round 6
// 276.490 us; speedup vs baseline: 1.0400x; 1.0400x over previous
//
#include <hip/hip_runtime.h>
#include <cstdint>
#include <cstddef>

// B=8, N=2048, C=512
// out = feature + softmax(Q K^T) @ V / sqrt(C),  Q = X Wq^T + bq etc.
// R16: density restructure. All prior rounds pinned at ~620 MFMA-cyc/SIMD
//      per phase vs ~1.3-1.6k cyc fixed phase overhead -> 22-25% MfmaUtil.
//      Fix: 2x MFMA per phase AND 4 waves/SIMD.
//  - gemm_qk10: 256x256 tile, BK=64, 1024 thr (16 waves, 4/SIMD),
//    per-wave 64x64 (acc 64 VGPR). Per phase/SIMD: 4x32 MFMA = 2480 cyc.
//    kk=1 frags reuse kk=0 registers (mid-phase lgkm0). 8 phases, grid 512
//    (2 rounds), 128 KB LDS dbuf, vmcnt(0) at phase end (covered: MFMA
//    2480 cyc > 900 HBM latency). R14's verified sync skeleton.
//  - gemm_pv10: 128d x 256q tile, BK=64, 1024 thr, per-wave 64x32,
//    grid 256 = 1/CU single round, 32-deep K-loop, 96 KB LDS.
//    P HBM-fetched once (4 d-sharers co-resident per XCD).
// prep / gemm_qkv unchanged.

typedef __bf16 bf16x8 __attribute__((ext_vector_type(8)));
typedef float f32x4 __attribute__((ext_vector_type(4)));
typedef short short4v __attribute__((ext_vector_type(4)));

__device__ __forceinline__ short f2b(float f) {
  union { float f; unsigned u; } u; u.f = f;
  unsigned r = (u.u + 0x7fffu + ((u.u >> 16) & 1u)) >> 16;  // RNE
  return (short)r;
}

#define GLDS(gptr, lptr) \
  __builtin_amdgcn_global_load_lds( \
      (const __attribute__((address_space(1))) unsigned int*)(const void*)(gptr), \
      (__attribute__((address_space(3))) unsigned int*)(void*)(lptr), 16, 0, 0)

// plain fragment load from [rows][64] XOR-swizzled LDS (gemm_qkv only).
__device__ __forceinline__ bf16x8 ldfrag64(const short* buf, int row, int kq) {
  return *(const bf16x8*)(buf + row * 64 + ((kq ^ (row & 7)) * 8));
}

// asm ds_read_b128 (invisible to SIInsertWaitcnts -> no auto vmcnt(0)
// drains after global_load_lds; completion guaranteed ONLY by the
// explicit lgkmcnt(0) that follows).
__device__ __forceinline__ bf16x8 ds_asm(const short* p) {
  bf16x8 r;
  asm volatile("ds_read_b128 %0, %1"
               : "=v"(r)
               : "v"((const __attribute__((address_space(3))) short*)(const void*)p));
  return r;
}
// [rows][64] XOR-swizzled buffer, asm variant.
__device__ __forceinline__ bf16x8 ldfrag64a(const short* buf, int row, int kq) {
  return ds_asm(buf + row * 64 + ((kq ^ (row & 7)) * 8));
}

#define LGKM0_SB() do { \
    asm volatile("s_waitcnt lgkmcnt(0)" ::: "memory"); \
    __builtin_amdgcn_sched_barrier(0); } while (0)
#define VMW0() asm volatile("s_waitcnt vmcnt(0)" ::: "memory")
#define SBAR() __builtin_amdgcn_s_barrier()
#define PRIO1() __builtin_amdgcn_s_setprio(1)
#define PRIO0() __builtin_amdgcn_s_setprio(0)

// ---------------- merged prep: feature->bf16, weights->bf16, bias pack, l=0 ----------------
__global__ __launch_bounds__(256) void prep(const float* __restrict__ f,
                                            const float* __restrict__ w0,
                                            const float* __restrict__ w1,
                                            const float* __restrict__ w2,
                                            const float* __restrict__ b0,
                                            const float* __restrict__ b1,
                                            const float* __restrict__ b2,
                                            short* __restrict__ Xb, short* __restrict__ Wb,
                                            float* __restrict__ biasP, float* __restrict__ l) {
  const int bid = blockIdx.x;
  const int t = threadIdx.x;
  if (bid < 8192) {                       // feature: 2097152 float4
    int i = bid * 256 + t;
    float4 v = ((const float4*)f)[i];
    short4v o = { f2b(v.x), f2b(v.y), f2b(v.z), f2b(v.w) };
    *(short4v*)(Xb + (size_t)i * 4) = o;
  } else if (bid < 8960) {                // weights: 196608 float4
    int i = (bid - 8192) * 256 + t;
    const float* src = (i < 65536) ? w0 : (i < 131072) ? w1 : w2;
    float4 v = ((const float4*)src)[i & 65535];
    short4v o = { f2b(v.x), f2b(v.y), f2b(v.z), f2b(v.w) };
    *(short4v*)(Wb + (size_t)i * 4) = o;
  } else {                                // 8 blocks: l zero (16384 f32) + bias (1536)
    int i = (bid - 8960) * 256 + t;       // 0..2047
    float4 z = { 0.f, 0.f, 0.f, 0.f };
    ((float4*)l)[i * 2] = z;
    ((float4*)l)[i * 2 + 1] = z;
    if (i < 1536) {
      const float* s = (i < 512) ? b0 : (i < 1024) ? b1 : b2;
      biasP[i] = s[i & 511];
    }
  }
}

// ---------------- fused QKV projection: 128x128 tile, BK=64 swizzled, 16x16x32 ----------------
__global__ __launch_bounds__(256) void gemm_qkv(const short* __restrict__ X,
                                                const short* __restrict__ Wall,
                                                const float* __restrict__ biasP,
                                                short* __restrict__ Out,
                                                short* __restrict__ VtOut) {
  __shared__ __align__(16) short Xs[128 * 64];
  __shared__ __align__(16) short Ws[128 * 64];
  const int z = blockIdx.z;
  const short* Wm = Wall + (size_t)z * 262144;
  const int m0 = blockIdx.y * 128, n0 = blockIdx.x * 128;
  const int t = threadIdx.x;
  const int lane = t & 63, w = t >> 6;
  const int wn = (w & 1) * 64, wm = (w >> 1) * 64;
  const int fr = lane & 15, l4 = lane >> 4;

  f32x4 acc[4][4] = {};

  for (int k0 = 0; k0 < 512; k0 += 64) {
    __syncthreads();
#pragma unroll
    for (int u = 0; u < 4; ++u) {
      int cc = t + u * 256;
      int r = cc >> 3, cs = cc & 7;
      int kk = ((cs ^ (r & 7)) * 8);
      GLDS(X + (size_t)(m0 + r) * 512 + k0 + kk, Xs + cc * 8);
      GLDS(Wm + (size_t)(n0 + r) * 512 + k0 + kk, Ws + cc * 8);
    }
    __syncthreads();
#pragma unroll
    for (int h = 0; h < 2; ++h) {
      bf16x8 wf[4], xf[4];
#pragma unroll
      for (int i = 0; i < 4; ++i) wf[i] = ldfrag64(Ws, wn + i * 16 + fr, h * 4 + l4);
#pragma unroll
      for (int j = 0; j < 4; ++j) xf[j] = ldfrag64(Xs, wm + j * 16 + fr, h * 4 + l4);
      if (z < 2) {
#pragma unroll
        for (int i = 0; i < 4; ++i)
#pragma unroll
          for (int j = 0; j < 4; ++j)
            acc[i][j] = __builtin_amdgcn_mfma_f32_16x16x32_bf16(wf[i], xf[j], acc[i][j], 0, 0, 0);
      } else {
#pragma unroll
        for (int i = 0; i < 4; ++i)
#pragma unroll
          for (int j = 0; j < 4; ++j)
            acc[i][j] = __builtin_amdgcn_mfma_f32_16x16x32_bf16(xf[i], wf[j], acc[i][j], 0, 0, 0);
      }
    }
  }

  const int rq = l4 * 4;
  if (z < 2) {
#pragma unroll
    for (int i = 0; i < 4; ++i) {
      int nb = n0 + wn + i * 16 + rq;
      float4 bs = *(const float4*)(biasP + z * 512 + nb);
#pragma unroll
      for (int j = 0; j < 4; ++j) {
        int m = m0 + wm + j * 16 + fr;
        short4v o = { f2b(acc[i][j][0] + bs.x), f2b(acc[i][j][1] + bs.y),
                      f2b(acc[i][j][2] + bs.z), f2b(acc[i][j][3] + bs.w) };
        *(short4v*)(Out + (size_t)z * 8388608 + (size_t)m * 512 + nb) = o;
      }
    }
  } else {
    const int zB = blockIdx.y >> 4;
    const int mb = m0 & 2047;
#pragma unroll
    for (int j = 0; j < 4; ++j) {
      int d = n0 + wn + j * 16 + fr;
      float bd = biasP[1024 + d];
#pragma unroll
      for (int i = 0; i < 4; ++i) {
        int mloc = mb + wm + i * 16 + rq;
        short4v o = { f2b(acc[i][j][0] + bd), f2b(acc[i][j][1] + bd),
                      f2b(acc[i][j][2] + bd), f2b(acc[i][j][3] + bd) };
        *(short4v*)(VtOut + (size_t)zB * 1048576 + (size_t)d * 2048 + mloc) = o;
      }
    }
  }
}

// ---------------- QK^T: 256x256 tile, BK=64, 16 waves (4/SIMD), dbuf ----------------
// A = K rows (keys), B = Q rows (queries). Waves 4(keys)x4(q), per-wave 64x64.
// Phase kt: [kk0 ds_reads of T(kt)] [GLDS T(kt+1)] SBAR lgkm0 [16 MFMA]
//           [kk1 ds_reads, reuse regs] lgkm0 [16 MFMA] VMW(0) SBAR.
// T(kt) data verified by phase kt-1's VMW(0)+SBAR. WAR on slot c^1: its
// readers (phase kt-1 kk1) drained at kt-1's 2nd lgkm0, before its closing
// SBAR; our GLDS issues after that barrier.
__global__ __launch_bounds__(1024) void gemm_qk10(const short* __restrict__ Q,
                                                  const short* __restrict__ Kb,
                                                  short* __restrict__ P,
                                                  float* __restrict__ l) {
  __shared__ __align__(16) short As[2][16384];  // keys    256x64, 32 KB each
  __shared__ __align__(16) short Bs[2][16384];  // queries 256x64
  const int id = blockIdx.x;      // 512 blocks; z == XCD (id&7)
  const int z = id & 7, r = id >> 3;
  const int m0 = (r & 7) * 256;   // keys
  const int n0 = (r >> 3) * 256;  // queries
  const short* __restrict__ A = Kb + (size_t)z * 1048576 + (size_t)m0 * 512;
  const short* __restrict__ B = Q + (size_t)z * 1048576 + (size_t)n0 * 512;
  const int t = threadIdx.x;
  const int lane = t & 63, w = t >> 6;
  const int aw = (w >> 2) * 64, bw = (w & 3) * 64;
  const int fr = lane & 15, l4 = lane >> 4;
  // staging: 4096 chunks (A 2048 + B 2048), 4/thread. Rows sr, sr+128.
  const int sr = t >> 3, sc = t & 7;
  const int swz = (sc ^ (sr & 7)) * 8;          // (sr+128)&7 == sr&7
  const short* pA = A + (size_t)sr * 512 + swz;
  const short* pB = B + (size_t)sr * 512 + swz;

#define QK_STG(buf, kt) do { \
    GLDS(pA + (kt) * 64, &As[(buf)][t * 8]); \
    GLDS(pA + (size_t)128 * 512 + (kt) * 64, &As[(buf)][(t + 1024) * 8]); \
    GLDS(pB + (kt) * 64, &Bs[(buf)][t * 8]); \
    GLDS(pB + (size_t)128 * 512 + (kt) * 64, &Bs[(buf)][(t + 1024) * 8]); \
  } while (0)

  f32x4 acc[4][4] = {};
  bf16x8 a[4], b[4];

  QK_STG(0, 0);
  VMW0();
  SBAR();

#pragma unroll 2
  for (int kt = 0; kt < 8; ++kt) {
    const int c = kt & 1;
    // kk = 0 reads (T(kt) verified landed by prev phase's VMW0+SBAR)
#pragma unroll
    for (int i = 0; i < 4; ++i) a[i] = ldfrag64a(&As[c][0], aw + i * 16 + fr, l4);
#pragma unroll
    for (int n = 0; n < 4; ++n) b[n] = ldfrag64a(&Bs[c][0], bw + n * 16 + fr, l4);
    if (kt < 7) QK_STG(c ^ 1, kt + 1);
    SBAR();
    LGKM0_SB();
    PRIO1();
#pragma unroll
    for (int i = 0; i < 4; ++i)
#pragma unroll
      for (int n = 0; n < 4; ++n)
        acc[i][n] = __builtin_amdgcn_mfma_f32_16x16x32_bf16(a[i], b[n], acc[i][n], 0, 0, 0);
    // kk = 1 reads, reusing the same registers
#pragma unroll
    for (int i = 0; i < 4; ++i) a[i] = ldfrag64a(&As[c][0], aw + i * 16 + fr, 4 + l4);
#pragma unroll
    for (int n = 0; n < 4; ++n) b[n] = ldfrag64a(&Bs[c][0], bw + n * 16 + fr, 4 + l4);
    LGKM0_SB();
#pragma unroll
    for (int i = 0; i < 4; ++i)
#pragma unroll
      for (int n = 0; n < 4; ++n)
        acc[i][n] = __builtin_amdgcn_mfma_f32_16x16x32_bf16(a[i], b[n], acc[i][n], 0, 0, 0);
    PRIO0();
    if (kt < 7) VMW0();
    SBAR();
  }
#undef QK_STG

  // epilogue: e = exp(score), store bf16 P[query][key], row-sum atomics.
  const float LOG2E = 1.4426950408889634f;
  float rs[4] = { 0.f, 0.f, 0.f, 0.f };
#pragma unroll
  for (int i = 0; i < 4; ++i) {
    const int key = m0 + aw + i * 16 + l4 * 4;
#pragma unroll
    for (int n = 0; n < 4; ++n) {
      const int q = n0 + bw + n * 16 + fr;
      short4v o;
      float part = 0.f;
#pragma unroll
      for (int rr = 0; rr < 4; ++rr) {
        float e = exp2f(acc[i][n][rr] * LOG2E);
        o[rr] = f2b(e);
        part += e;
      }
      *(short4v*)(P + (size_t)z * 4194304 + (size_t)q * 2048 + key) = o;
      rs[n] += part;
    }
  }
#pragma unroll
  for (int n = 0; n < 4; ++n) {
    rs[n] += __shfl_xor(rs[n], 16);
    rs[n] += __shfl_xor(rs[n], 32);
  }
  if (l4 == 0) {
#pragma unroll
    for (int n = 0; n < 4; ++n)
      atomicAdd(&l[z * 2048 + n0 + bw + n * 16 + fr], rs[n]);
  }
}

// ---------------- PV: 128(d) x 256(q) tile, BK=64, 16 waves, K=2048 ----------------
// A = Vt d-rows, B = P q-rows. Waves 2(d)x8(q), per-wave 64x32.
// Same phase skeleton as gemm_qk10; 32 phases; grid 256 = 1/CU, 1 round.
__global__ __launch_bounds__(1024) void gemm_pv10(const short* __restrict__ Pm,
                                                  const short* __restrict__ Vt,
                                                  const float* __restrict__ l,
                                                  const float* __restrict__ resid,
                                                  float* __restrict__ out, float scale) {
  __shared__ __align__(16) short As[2][8192];   // Vt 128x64, 16 KB each
  __shared__ __align__(16) short Bs[2][16384];  // P  256x64, 32 KB each
  const int id = blockIdx.x;      // 256 blocks; z == XCD (id&7)
  const int z = id & 7, r = id >> 3;
  const int d0 = (r & 3) * 128;
  const int q0 = (r >> 2) * 256;
  const short* __restrict__ A = Vt + (size_t)z * 1048576 + (size_t)d0 * 2048;
  const short* __restrict__ B = Pm + (size_t)z * 4194304 + (size_t)q0 * 2048;
  const int t = threadIdx.x;
  const int lane = t & 63, w = t >> 6;
  const int aw = (w >> 3) * 64, bw = (w & 7) * 32;
  const int fr = lane & 15, l4 = lane >> 4;
  // staging: A 1024 chunks (1/thread), B 2048 chunks (2/thread).
  const int sr = t >> 3, sc = t & 7;
  const int swz = (sc ^ (sr & 7)) * 8;
  const short* pA = A + (size_t)sr * 2048 + swz;
  const short* pB = B + (size_t)sr * 2048 + swz;

#define PV_STG(buf, kt) do { \
    GLDS(pA + (kt) * 64, &As[(buf)][t * 8]); \
    GLDS(pB + (kt) * 64, &Bs[(buf)][t * 8]); \
    GLDS(pB + (size_t)128 * 2048 + (kt) * 64, &Bs[(buf)][(t + 1024) * 8]); \
  } while (0)

  f32x4 acc[4][2] = {};
  bf16x8 a[4], b[2];

  PV_STG(0, 0);
  VMW0();
  SBAR();

#pragma unroll 2
  for (int kt = 0; kt < 32; ++kt) {
    const int c = kt & 1;
#pragma unroll
    for (int i = 0; i < 4; ++i) a[i] = ldfrag64a(&As[c][0], aw + i * 16 + fr, l4);
#pragma unroll
    for (int n = 0; n < 2; ++n) b[n] = ldfrag64a(&Bs[c][0], bw + n * 16 + fr, l4);
    if (kt < 31) PV_STG(c ^ 1, kt + 1);
    SBAR();
    LGKM0_SB();
    PRIO1();
#pragma unroll
    for (int i = 0; i < 4; ++i)
#pragma unroll
      for (int n = 0; n < 2; ++n)
        acc[i][n] = __builtin_amdgcn_mfma_f32_16x16x32_bf16(a[i], b[n], acc[i][n], 0, 0, 0);
#pragma unroll
    for (int i = 0; i < 4; ++i) a[i] = ldfrag64a(&As[c][0], aw + i * 16 + fr, 4 + l4);
#pragma unroll
    for (int n = 0; n < 2; ++n) b[n] = ldfrag64a(&Bs[c][0], bw + n * 16 + fr, 4 + l4);
    LGKM0_SB();
#pragma unroll
    for (int i = 0; i < 4; ++i)
#pragma unroll
      for (int n = 0; n < 2; ++n)
        acc[i][n] = __builtin_amdgcn_mfma_f32_16x16x32_bf16(a[i], b[n], acc[i][n], 0, 0, 0);
    PRIO0();
    if (kt < 31) VMW0();
    SBAR();
  }
#undef PV_STG

  // epilogue: out = resid + acc * (scale / l[q])
  float linv[2];
#pragma unroll
  for (int n = 0; n < 2; ++n)
    linv[n] = scale / l[z * 2048 + q0 + bw + n * 16 + fr];
#pragma unroll
  for (int n = 0; n < 2; ++n) {
    const int q = q0 + bw + n * 16 + fr;
#pragma unroll
    for (int i = 0; i < 4; ++i) {
      const int d = d0 + aw + i * 16 + l4 * 4;
      const size_t idx = (size_t)z * 1048576 + (size_t)q * 512 + d;
      float4 rv = *(const float4*)(resid + idx);
      float4 o = { rv.x + acc[i][n][0] * linv[n], rv.y + acc[i][n][1] * linv[n],
                   rv.z + acc[i][n][2] * linv[n], rv.w + acc[i][n][3] * linv[n] };
      *(float4*)(out + idx) = o;
    }
  }
}

extern "C" void kernel_launch(void* const* d_in, const int* in_sizes, int n_in,
                              void* d_out, int out_size, void* d_ws, size_t ws_size,
                              hipStream_t stream) {
  const float* feature = (const float*)d_in[0];
  const float* wq = (const float*)d_in[1];
  const float* bq = (const float*)d_in[2];
  const float* wk = (const float*)d_in[3];
  const float* bk = (const float*)d_in[4];
  const float* wv = (const float*)d_in[5];
  const float* bv = (const float*)d_in[6];
  float* out = (float*)d_out;

  const size_t MN = (size_t)16384 * 512;
  short* Xb = (short*)d_ws;       // MN
  short* Wb = Xb + MN;            // 3 * 262144
  short* Q = Wb + 786432;         // MN (K follows contiguously)
  short* K = Q + MN;
  short* Vt = K + MN;             // [8][512][2048]
  short* P = Vt + MN;             // [8][2048][2048] unnormalized exp
  float* biasP = (float*)(P + (size_t)8 * 2048 * 2048);  // [3][512]
  float* l = biasP + 1536;        // [8*2048] row sums of exp

  prep<<<8968, 256, 0, stream>>>(feature, wq, wk, wv, bq, bk, bv, Xb, Wb, biasP, l);

  gemm_qkv<<<dim3(4, 128, 3), 256, 0, stream>>>(Xb, Wb, biasP, Q, Vt);
  gemm_qk10<<<512, 1024, 0, stream>>>(Q, K, P, l);

  const float iscl = 0.044194173824159216f;  // 1/sqrt(512)
  gemm_pv10<<<256, 1024, 0, stream>>>(P, Vt, l, feature, out, iscl);
}

// Round 7
// 230.399 us; speedup vs baseline: 1.2480x; 1.2001x over previous
//
#include <hip/hip_runtime.h>
#include <cstdint>
#include <cstddef>

// B=8, N=2048, C=512
// out = feature + softmax(Q K^T) @ V / sqrt(C),  Q = X Wq^T + bq etc.
// R17: revert qk/pv to R12's verified kernels (best total 229.9 µs);
//      port gemm_qkv onto R12-qk8's verified 256x256 4-phase pipelined
//      skeleton (same staging macros / vmcnt schedule / tails; only the
//      operand roles swap per z and the epilogues differ).
//      z<2 (Q,K): A=W rows (n quad-contig in C), B=X rows.
//      z==2 (V):  A=X rows (m quad-contig)  -> writes Vt[d][token].
// prep unchanged.

typedef __bf16 bf16x8 __attribute__((ext_vector_type(8)));
typedef float f32x4 __attribute__((ext_vector_type(4)));
typedef short short4v __attribute__((ext_vector_type(4)));

__device__ __forceinline__ short f2b(float f) {
  union { float f; unsigned u; } u; u.f = f;
  unsigned r = (u.u + 0x7fffu + ((u.u >> 16) & 1u)) >> 16;  // RNE
  return (short)r;
}

#define GLDS(gptr, lptr) \
  __builtin_amdgcn_global_load_lds( \
      (const __attribute__((address_space(1))) unsigned int*)(const void*)(gptr), \
      (__attribute__((address_space(3))) unsigned int*)(void*)(lptr), 16, 0, 0)

// asm fragment load: invisible to SIInsertWaitcnts -> no auto vmcnt drain.
// Completion is ONLY guaranteed by the explicit lgkmcnt(0) below.
__device__ __forceinline__ bf16x8 ldfrag_a(const short* buf, int row, int kq) {
  const short* p = buf + row * 64 + ((kq ^ (row & 7)) * 8);
  bf16x8 r;
  asm volatile("ds_read_b128 %0, %1"
               : "=v"(r)
               : "v"((const __attribute__((address_space(3))) short*)(const void*)p));
  return r;
}

#define LGKM0_SB() do { \
    asm volatile("s_waitcnt lgkmcnt(0)" ::: "memory"); \
    __builtin_amdgcn_sched_barrier(0); } while (0)
#define VMW(n) asm volatile("s_waitcnt vmcnt(" #n ")" ::: "memory")
#define SBAR() __builtin_amdgcn_s_barrier()
#define PRIO1() __builtin_amdgcn_s_setprio(1)
#define PRIO0() __builtin_amdgcn_s_setprio(0)

__device__ __forceinline__ void ldA4(bf16x8 (&a)[4][2], const short* buf, int rb, int l4) {
#pragma unroll
  for (int j = 0; j < 4; ++j)
#pragma unroll
    for (int kk = 0; kk < 2; ++kk) a[j][kk] = ldfrag_a(buf, rb + j * 16, kk * 4 + l4);
}
__device__ __forceinline__ void ld2(bf16x8 (&b)[2][2], const short* buf, int rb, int l4) {
#pragma unroll
  for (int n = 0; n < 2; ++n)
#pragma unroll
    for (int kk = 0; kk < 2; ++kk) b[n][kk] = ldfrag_a(buf, rb + n * 16, kk * 4 + l4);
}
// kk-outer: dependent same-acc MFMAs are 8 apart; per-acc k-order unchanged.
__device__ __forceinline__ void mm42(f32x4 (&acc)[8][4], const bf16x8 (&a)[4][2],
                                     const bf16x8 (&b)[2][2], int io, int no) {
#pragma unroll
  for (int kk = 0; kk < 2; ++kk)
#pragma unroll
    for (int j = 0; j < 4; ++j)
#pragma unroll
      for (int n = 0; n < 2; ++n)
        acc[io + j][no + n] = __builtin_amdgcn_mfma_f32_16x16x32_bf16(
            a[j][kk], b[n][kk], acc[io + j][no + n], 0, 0, 0);
}
__device__ __forceinline__ void mm22(f32x4 (&acc)[4][4], const bf16x8 (&a)[2][2],
                                     const bf16x8 (&b)[2][2], int io, int no) {
#pragma unroll
  for (int kk = 0; kk < 2; ++kk)
#pragma unroll
    for (int j = 0; j < 2; ++j)
#pragma unroll
      for (int n = 0; n < 2; ++n)
        acc[io + j][no + n] = __builtin_amdgcn_mfma_f32_16x16x32_bf16(
            a[j][kk], b[n][kk], acc[io + j][no + n], 0, 0, 0);
}

// ---------------- merged prep: feature->bf16, weights->bf16, bias pack, l=0 ----------------
__global__ __launch_bounds__(256) void prep(const float* __restrict__ f,
                                            const float* __restrict__ w0,
                                            const float* __restrict__ w1,
                                            const float* __restrict__ w2,
                                            const float* __restrict__ b0,
                                            const float* __restrict__ b1,
                                            const float* __restrict__ b2,
                                            short* __restrict__ Xb, short* __restrict__ Wb,
                                            float* __restrict__ biasP, float* __restrict__ l) {
  const int bid = blockIdx.x;
  const int t = threadIdx.x;
  if (bid < 8192) {                       // feature: 2097152 float4
    int i = bid * 256 + t;
    float4 v = ((const float4*)f)[i];
    short4v o = { f2b(v.x), f2b(v.y), f2b(v.z), f2b(v.w) };
    *(short4v*)(Xb + (size_t)i * 4) = o;
  } else if (bid < 8960) {                // weights: 196608 float4
    int i = (bid - 8192) * 256 + t;
    const float* src = (i < 65536) ? w0 : (i < 131072) ? w1 : w2;
    float4 v = ((const float4*)src)[i & 65535];
    short4v o = { f2b(v.x), f2b(v.y), f2b(v.z), f2b(v.w) };
    *(short4v*)(Wb + (size_t)i * 4) = o;
  } else {                                // 8 blocks: l zero (16384 f32) + bias (1536)
    int i = (bid - 8960) * 256 + t;       // 0..2047
    float4 z = { 0.f, 0.f, 0.f, 0.f };
    ((float4*)l)[i * 2] = z;
    ((float4*)l)[i * 2 + 1] = z;
    if (i < 1536) {
      const float* s = (i < 512) ? b0 : (i < 1024) ? b1 : b2;
      biasP[i] = s[i & 511];
    }
  }
}

// ---------------- fused QKV projection: 256x256 tile, 4-phase pipelined (R12 skeleton) ----
// z<2: A = W rows (output dim n), B = X rows (tokens m). C-row = n (quad-contig).
// z==2: A = X rows (tokens), B = W rows (d).        C-row = m -> Vt[d][token].
// Phases/K-tile: (A0,B0)(A0,B1)(A1,B1)(A1,B0); stage slots ph1->T(kt+1).A1,
// ph2->T(kt+2).A0, ph3->T(kt+2).B0, ph4->T(kt+2).B1; vmcnt(6) at ph4 only.
__global__ __launch_bounds__(512, 2) void gemm_qkv256(const short* __restrict__ X,
                                                      const short* __restrict__ Wall,
                                                      const float* __restrict__ biasP,
                                                      short* __restrict__ Out,
                                                      short* __restrict__ VtOut) {
  __shared__ __align__(16) short As[2][16384];  // A rows 256x64 per buffer
  __shared__ __align__(16) short Bs[2][16384];  // B rows
  // XCD remap: 384 blocks (384 % 8 == 0 -> bijective).
  const int id = blockIdx.x + blockIdx.y * 2 + blockIdx.z * 128;
  const int swz = (id & 7) * 48 + (id >> 3);
  const int z = swz >> 7;               // 0..2
  const int rem = swz & 127;
  const int m0 = (rem >> 1) * 256;      // token rows
  const int n0 = (rem & 1) * 256;       // output dim
  const short* __restrict__ Wm = Wall + (size_t)z * 262144 + (size_t)n0 * 512;
  const short* __restrict__ Xm = X + (size_t)m0 * 512;
  const short* __restrict__ Ag = (z < 2) ? Wm : Xm;
  const short* __restrict__ Bg = (z < 2) ? Xm : Wm;
  const int t = threadIdx.x;
  const int lane = t & 63, w = t >> 6;
  const int aw = (w >> 2) * 64, bw = (w & 3) * 32;
  const int fr = lane & 15, l4 = lane >> 4;
  const int r0 = t >> 3;
  const int kswz = ((t & 7) ^ (r0 & 7)) * 8;  // pre-swizzled global source chunk
  const short* pA = Ag + (size_t)r0 * 512 + kswz;
  const short* pB = Bg + (size_t)r0 * 512 + kswz;

#define QV_STG_A(buf, h, kt) do { \
    GLDS(pA + (size_t)((h) * 128) * 512 + (kt) * 64, &As[(buf)][(h) * 8192 + t * 8]); \
    GLDS(pA + (size_t)((h) * 128 + 64) * 512 + (kt) * 64, &As[(buf)][(h) * 8192 + 4096 + t * 8]); \
  } while (0)
#define QV_STG_B(buf, h, kt) do { \
    GLDS(pB + (size_t)((h) * 128) * 512 + (kt) * 64, &Bs[(buf)][(h) * 8192 + t * 8]); \
    GLDS(pB + (size_t)((h) * 128 + 64) * 512 + (kt) * 64, &Bs[(buf)][(h) * 8192 + 4096 + t * 8]); \
  } while (0)

  f32x4 acc[8][4] = {};

  // prologue: T0.{A0,B0,B1,A1}, T1.{A0,B0,B1} = 14 loads; wait ALL of T0.
  QV_STG_A(0, 0, 0); QV_STG_B(0, 0, 0); QV_STG_B(0, 1, 0); QV_STG_A(0, 1, 0);
  QV_STG_A(1, 0, 1); QV_STG_B(1, 0, 1); QV_STG_B(1, 1, 1);
  VMW(6);
  SBAR();

  bf16x8 af[4][2], b0[2][2], b1[2][2];
  for (int kt = 0; kt < 6; ++kt) {
    const int c = kt & 1;
    const short* Ac = &As[c][0];
    const short* Bc = &Bs[c][0];
    // ph1 (A0,B0)
    ldA4(af, Ac, aw + fr, l4); ld2(b0, Bc, bw + fr, l4);
    QV_STG_A(c ^ 1, 1, kt + 1);
    SBAR(); LGKM0_SB(); PRIO1(); mm42(acc, af, b0, 0, 0); PRIO0(); SBAR();
    // ph2 (A0,B1)
    ld2(b1, Bc, 128 + bw + fr, l4);
    QV_STG_A(c, 0, kt + 2);
    SBAR(); LGKM0_SB(); PRIO1(); mm42(acc, af, b1, 0, 2); PRIO0(); SBAR();
    // ph3 (A1,B1)
    ldA4(af, Ac, 128 + aw + fr, l4);
    QV_STG_B(c, 0, kt + 2);
    SBAR(); LGKM0_SB(); PRIO1(); mm42(acc, af, b1, 4, 2); PRIO0(); SBAR();
    // ph4 (A1,B0) - frags register-held; wait ALL of T(kt+1).
    QV_STG_B(c, 1, kt + 2);
    VMW(6);
    SBAR(); PRIO1(); mm42(acc, af, b0, 4, 0); PRIO0(); SBAR();
  }
  {  // kt = 6 (buf 0): only T7.A1 left; ph4 waits ALL of T7 -> vmcnt(0).
    const short *Ac = &As[0][0], *Bc = &Bs[0][0];
    ldA4(af, Ac, aw + fr, l4); ld2(b0, Bc, bw + fr, l4);
    QV_STG_A(1, 1, 7);
    SBAR(); LGKM0_SB(); PRIO1(); mm42(acc, af, b0, 0, 0); PRIO0(); SBAR();
    ld2(b1, Bc, 128 + bw + fr, l4);
    SBAR(); LGKM0_SB(); PRIO1(); mm42(acc, af, b1, 0, 2); PRIO0(); SBAR();
    ldA4(af, Ac, 128 + aw + fr, l4);
    SBAR(); LGKM0_SB(); PRIO1(); mm42(acc, af, b1, 4, 2); PRIO0(); SBAR();
    VMW(0);
    SBAR(); PRIO1(); mm42(acc, af, b0, 4, 0); PRIO0(); SBAR();
  }
  {  // kt = 7 (buf 1): no staging, no vmem waits.
    const short *Ac = &As[1][0], *Bc = &Bs[1][0];
    ldA4(af, Ac, aw + fr, l4); ld2(b0, Bc, bw + fr, l4);
    SBAR(); LGKM0_SB(); PRIO1(); mm42(acc, af, b0, 0, 0); PRIO0(); SBAR();
    ld2(b1, Bc, 128 + bw + fr, l4);
    SBAR(); LGKM0_SB(); PRIO1(); mm42(acc, af, b1, 0, 2); PRIO0(); SBAR();
    ldA4(af, Ac, 128 + aw + fr, l4);
    SBAR(); LGKM0_SB(); PRIO1(); mm42(acc, af, b1, 4, 2); PRIO0();
    mm42(acc, af, b0, 4, 0);
  }
#undef QV_STG_A
#undef QV_STG_B

  if (z < 2) {
    // C-row = n (quad-contig), C-col = m.
#pragma unroll
    for (int i = 0; i < 8; ++i) {
      const int nb = n0 + aw + (i & 3) * 16 + (i >> 2) * 128 + l4 * 4;
      float4 bs = *(const float4*)(biasP + z * 512 + nb);
#pragma unroll
      for (int n = 0; n < 4; ++n) {
        const int m = m0 + bw + (n & 1) * 16 + (n >> 1) * 128 + fr;
        short4v o = { f2b(acc[i][n][0] + bs.x), f2b(acc[i][n][1] + bs.y),
                      f2b(acc[i][n][2] + bs.z), f2b(acc[i][n][3] + bs.w) };
        *(short4v*)(Out + (size_t)z * 8388608 + (size_t)m * 512 + nb) = o;
      }
    }
  } else {
    // C-row = m (quad-contig), C-col = d -> Vt[batch][d][token].
    const int zB = m0 >> 11;
    const int mb = m0 & 2047;
#pragma unroll
    for (int n = 0; n < 4; ++n) {
      const int d = n0 + bw + (n & 1) * 16 + (n >> 1) * 128 + fr;
      const float bd = biasP[1024 + d];
#pragma unroll
      for (int i = 0; i < 8; ++i) {
        const int mloc = mb + aw + (i & 3) * 16 + (i >> 2) * 128 + l4 * 4;
        short4v o = { f2b(acc[i][n][0] + bd), f2b(acc[i][n][1] + bd),
                      f2b(acc[i][n][2] + bd), f2b(acc[i][n][3] + bd) };
        *(short4v*)(VtOut + (size_t)zB * 1048576 + (size_t)d * 2048 + mloc) = o;
      }
    }
  }
}

// ---------------- QK^T: 256x256 tile, 4-phase/K-tile pipelined (R12 verbatim) ----------------
__global__ __launch_bounds__(512, 2) void gemm_qk8(const short* __restrict__ Q,
                                                   const short* __restrict__ Kb,
                                                   short* __restrict__ P,
                                                   float* __restrict__ l) {
  __shared__ __align__(16) short As[2][16384];  // keys   256x64 per buffer
  __shared__ __align__(16) short Bs[2][16384];  // queries
  // XCD remap: dispatch id -> one batch z per XCD (Q_z+K_z = 4MB = one L2).
  const int id = blockIdx.x + blockIdx.y * 8 + blockIdx.z * 64;
  const int swz = (id & 7) * 64 + (id >> 3);
  const int z = swz >> 6;
  const int m0 = ((swz >> 3) & 7) * 256;  // keys
  const int n0 = (swz & 7) * 256;         // queries
  const short* __restrict__ A = Kb + (size_t)z * 1048576;
  const short* __restrict__ B = Q + (size_t)z * 1048576;
  const int t = threadIdx.x;
  const int lane = t & 63, w = t >> 6;
  const int aw = (w >> 2) * 64, bw = (w & 3) * 32;
  const int fr = lane & 15, l4 = lane >> 4;
  const int r0 = t >> 3;
  const int kswz = ((t & 7) ^ (r0 & 7)) * 8;  // pre-swizzled global source chunk
  const short* pA = A + (size_t)(m0 + r0) * 512 + kswz;
  const short* pB = B + (size_t)(n0 + r0) * 512 + kswz;

#define QK_STG_A(buf, h, kt) do { \
    GLDS(pA + (size_t)((h) * 128) * 512 + (kt) * 64, &As[(buf)][(h) * 8192 + t * 8]); \
    GLDS(pA + (size_t)((h) * 128 + 64) * 512 + (kt) * 64, &As[(buf)][(h) * 8192 + 4096 + t * 8]); \
  } while (0)
#define QK_STG_B(buf, h, kt) do { \
    GLDS(pB + (size_t)((h) * 128) * 512 + (kt) * 64, &Bs[(buf)][(h) * 8192 + t * 8]); \
    GLDS(pB + (size_t)((h) * 128 + 64) * 512 + (kt) * 64, &Bs[(buf)][(h) * 8192 + 4096 + t * 8]); \
  } while (0)

  f32x4 acc[8][4] = {};

  // prologue: T0.{A0,B0,B1,A1}, T1.{A0,B0,B1} = 14 loads; wait ALL of T0.
  QK_STG_A(0, 0, 0); QK_STG_B(0, 0, 0); QK_STG_B(0, 1, 0); QK_STG_A(0, 1, 0);
  QK_STG_A(1, 0, 1); QK_STG_B(1, 0, 1); QK_STG_B(1, 1, 1);
  VMW(6);
  SBAR();

  bf16x8 af[4][2], b0[2][2], b1[2][2];
  for (int kt = 0; kt < 6; ++kt) {
    const int c = kt & 1;
    const short* Ac = &As[c][0];
    const short* Bc = &Bs[c][0];
    // ph1 (A0,B0)
    ldA4(af, Ac, aw + fr, l4); ld2(b0, Bc, bw + fr, l4);
    QK_STG_A(c ^ 1, 1, kt + 1);
    SBAR(); LGKM0_SB(); PRIO1(); mm42(acc, af, b0, 0, 0); PRIO0(); SBAR();
    // ph2 (A0,B1)
    ld2(b1, Bc, 128 + bw + fr, l4);
    QK_STG_A(c, 0, kt + 2);
    SBAR(); LGKM0_SB(); PRIO1(); mm42(acc, af, b1, 0, 2); PRIO0(); SBAR();
    // ph3 (A1,B1)
    ldA4(af, Ac, 128 + aw + fr, l4);
    QK_STG_B(c, 0, kt + 2);
    SBAR(); LGKM0_SB(); PRIO1(); mm42(acc, af, b1, 4, 2); PRIO0(); SBAR();
    // ph4 (A1,B0) - frags register-held; wait ALL of T(kt+1).
    QK_STG_B(c, 1, kt + 2);
    VMW(6);
    SBAR(); PRIO1(); mm42(acc, af, b0, 4, 0); PRIO0(); SBAR();
  }
  {  // kt = 6 (buf 0): only T7.A1 left; ph4 waits ALL of T7 -> vmcnt(0).
    const short *Ac = &As[0][0], *Bc = &Bs[0][0];
    ldA4(af, Ac, aw + fr, l4); ld2(b0, Bc, bw + fr, l4);
    QK_STG_A(1, 1, 7);
    SBAR(); LGKM0_SB(); PRIO1(); mm42(acc, af, b0, 0, 0); PRIO0(); SBAR();
    ld2(b1, Bc, 128 + bw + fr, l4);
    SBAR(); LGKM0_SB(); PRIO1(); mm42(acc, af, b1, 0, 2); PRIO0(); SBAR();
    ldA4(af, Ac, 128 + aw + fr, l4);
    SBAR(); LGKM0_SB(); PRIO1(); mm42(acc, af, b1, 4, 2); PRIO0(); SBAR();
    VMW(0);
    SBAR(); PRIO1(); mm42(acc, af, b0, 4, 0); PRIO0(); SBAR();
  }
  {  // kt = 7 (buf 1): no staging, no vmem waits.
    const short *Ac = &As[1][0], *Bc = &Bs[1][0];
    ldA4(af, Ac, aw + fr, l4); ld2(b0, Bc, bw + fr, l4);
    SBAR(); LGKM0_SB(); PRIO1(); mm42(acc, af, b0, 0, 0); PRIO0(); SBAR();
    ld2(b1, Bc, 128 + bw + fr, l4);
    SBAR(); LGKM0_SB(); PRIO1(); mm42(acc, af, b1, 0, 2); PRIO0(); SBAR();
    ldA4(af, Ac, 128 + aw + fr, l4);
    SBAR(); LGKM0_SB(); PRIO1(); mm42(acc, af, b1, 4, 2); PRIO0();
    mm42(acc, af, b0, 4, 0);
  }
#undef QK_STG_A
#undef QK_STG_B

  // epilogue: e = exp(score), store bf16 P[query][key], row-sum atomics.
  const float LOG2E = 1.4426950408889634f;
  float rs[4] = { 0.f, 0.f, 0.f, 0.f };
#pragma unroll
  for (int i = 0; i < 8; ++i) {
    const int key = m0 + aw + (i & 3) * 16 + (i >> 2) * 128 + l4 * 4;
#pragma unroll
    for (int n = 0; n < 4; ++n) {
      const int q = n0 + bw + (n & 1) * 16 + (n >> 1) * 128 + fr;
      short4v o;
      float part = 0.f;
#pragma unroll
      for (int r = 0; r < 4; ++r) {
        float e = exp2f(acc[i][n][r] * LOG2E);
        o[r] = f2b(e);
        part += e;
      }
      *(short4v*)(P + (size_t)z * 4194304 + (size_t)q * 2048 + key) = o;
      rs[n] += part;
    }
  }
#pragma unroll
  for (int n = 0; n < 4; ++n) {
    rs[n] += __shfl_xor(rs[n], 16);
    rs[n] += __shfl_xor(rs[n], 32);
  }
  if (l4 == 0) {
#pragma unroll
    for (int n = 0; n < 4; ++n)
      atomicAdd(&l[z * 2048 + n0 + bw + (n & 1) * 16 + (n >> 1) * 128 + fr], rs[n]);
  }
}

// ---------------- PV: 128(d) x 256(q) tile, 2-phase/K-tile pipelined (R12 verbatim) --------
__global__ __launch_bounds__(512, 2) void gemm_pv8(const short* __restrict__ Pm,
                                                   const short* __restrict__ Vt,
                                                   const float* __restrict__ l,
                                                   const float* __restrict__ resid,
                                                   float* __restrict__ out, float scale) {
  __shared__ __align__(16) short As[2][8192];   // Vt rows: 128x64
  __shared__ __align__(16) short Bs[2][16384];  // P rows: 256x64
  // XCD remap: one batch z per XCD -> all 32 z-blocks co-resident, P rows
  // fetched once into that XCD's L2 and read by its 4 d-tiles.
  const int id = blockIdx.x + blockIdx.y * 4 + blockIdx.z * 32;
  const int swz = (id & 7) * 32 + (id >> 3);
  const int z = swz >> 5;
  const int d0 = (swz & 3) * 128;
  const int n0 = ((swz >> 2) & 7) * 256;
  const short* __restrict__ A = Vt + (size_t)z * 1048576;  // [512][2048]
  const short* __restrict__ B = Pm + (size_t)z * 4194304;  // [2048][2048]
  const int t = threadIdx.x;
  const int lane = t & 63, w = t >> 6;
  const int aw = (w >> 2) * 32, bw = (w & 3) * 32;
  const int fr = lane & 15, l4 = lane >> 4;
  const int r0 = t >> 3;
  const int kswz = ((t & 7) ^ (r0 & 7)) * 8;
  const short* pA = A + (size_t)(d0 + r0) * 2048 + kswz;
  const short* pB = B + (size_t)(n0 + r0) * 2048 + kswz;

#define PV_STG_A(buf, h, kt) \
    GLDS(pA + (size_t)((h) * 64) * 2048 + (kt) * 64, &As[(buf)][(h) * 4096 + t * 8])
#define PV_STG_B(buf, h, kt) do { \
    GLDS(pB + (size_t)((h) * 128) * 2048 + (kt) * 64, &Bs[(buf)][(h) * 8192 + t * 8]); \
    GLDS(pB + (size_t)((h) * 128 + 64) * 2048 + (kt) * 64, &Bs[(buf)][(h) * 8192 + 4096 + t * 8]); \
  } while (0)

  f32x4 acc[4][4] = {};

  // prologue: T0 (6 loads) + T1.{A0,B0,B1} (5) = 11; wait ALL of T0 -> vmcnt(5).
  PV_STG_A(0, 0, 0); PV_STG_B(0, 0, 0); PV_STG_B(0, 1, 0); PV_STG_A(0, 1, 0);
  PV_STG_A(1, 0, 1); PV_STG_B(1, 0, 1); PV_STG_B(1, 1, 1);
  VMW(5);
  SBAR();

  bf16x8 a[2][2], b0[2][2], b1[2][2];
  for (int kt = 0; kt < 30; ++kt) {
    const int c = kt & 1;
    const short* Ac = &As[c][0];
    const short* Bc = &Bs[c][0];
    // pha (A0 x {b0,b1})
    ld2(a, Ac, aw + fr, l4); ld2(b0, Bc, bw + fr, l4); ld2(b1, Bc, 128 + bw + fr, l4);
    PV_STG_A(c ^ 1, 1, kt + 1);
    SBAR(); LGKM0_SB(); PRIO1();
    mm22(acc, a, b0, 0, 0); mm22(acc, a, b1, 0, 2);
    PRIO0(); SBAR();
    // phb (A1 x {b1,b0}); stage T(kt+2); single wait for ALL T(kt+1).
    ld2(a, Ac, 64 + aw + fr, l4);
    PV_STG_A(c, 0, kt + 2);
    PV_STG_B(c, 0, kt + 2);
    PV_STG_B(c, 1, kt + 2);
    VMW(5);
    SBAR(); LGKM0_SB(); PRIO1();
    mm22(acc, a, b1, 2, 2); mm22(acc, a, b0, 2, 0);
    PRIO0(); SBAR();
  }
  {  // kt = 30 (buf 0): only T31.A1 left; phb waits ALL T31 -> vmcnt(0).
    const short *Ac = &As[0][0], *Bc = &Bs[0][0];
    ld2(a, Ac, aw + fr, l4); ld2(b0, Bc, bw + fr, l4); ld2(b1, Bc, 128 + bw + fr, l4);
    PV_STG_A(1, 1, 31);
    SBAR(); LGKM0_SB(); PRIO1();
    mm22(acc, a, b0, 0, 0); mm22(acc, a, b1, 0, 2);
    PRIO0(); SBAR();
    ld2(a, Ac, 64 + aw + fr, l4);
    VMW(0);
    SBAR(); LGKM0_SB(); PRIO1();
    mm22(acc, a, b1, 2, 2); mm22(acc, a, b0, 2, 0);
    PRIO0(); SBAR();
  }
  {  // kt = 31 (buf 1): no staging, no vmem waits.
    const short *Ac = &As[1][0], *Bc = &Bs[1][0];
    ld2(a, Ac, aw + fr, l4); ld2(b0, Bc, bw + fr, l4); ld2(b1, Bc, 128 + bw + fr, l4);
    SBAR(); LGKM0_SB(); PRIO1();
    mm22(acc, a, b0, 0, 0); mm22(acc, a, b1, 0, 2);
    PRIO0(); SBAR();
    ld2(a, Ac, 64 + aw + fr, l4);
    LGKM0_SB(); PRIO1();
    mm22(acc, a, b1, 2, 2); mm22(acc, a, b0, 2, 0);
    PRIO0();
  }
#undef PV_STG_A
#undef PV_STG_B

  // epilogue: out = resid + acc * (scale / l[q])
  float linv[4];
#pragma unroll
  for (int n = 0; n < 4; ++n) {
    const int q = n0 + bw + (n & 1) * 16 + (n >> 1) * 128 + fr;
    linv[n] = scale / l[z * 2048 + q];
  }
#pragma unroll
  for (int n = 0; n < 4; ++n) {
    const int q = n0 + bw + (n & 1) * 16 + (n >> 1) * 128 + fr;
#pragma unroll
    for (int i = 0; i < 4; ++i) {
      const int d = d0 + aw + (i & 1) * 16 + (i >> 1) * 64 + l4 * 4;
      const size_t idx = (size_t)z * 1048576 + (size_t)q * 512 + d;
      float4 rv = *(const float4*)(resid + idx);
      float4 o = { rv.x + acc[i][n][0] * linv[n], rv.y + acc[i][n][1] * linv[n],
                   rv.z + acc[i][n][2] * linv[n], rv.w + acc[i][n][3] * linv[n] };
      *(float4*)(out + idx) = o;
    }
  }
}

extern "C" void kernel_launch(void* const* d_in, const int* in_sizes, int n_in,
                              void* d_out, int out_size, void* d_ws, size_t ws_size,
                              hipStream_t stream) {
  const float* feature = (const float*)d_in[0];
  const float* wq = (const float*)d_in[1];
  const float* bq = (const float*)d_in[2];
  const float* wk = (const float*)d_in[3];
  const float* bk = (const float*)d_in[4];
  const float* wv = (const float*)d_in[5];
  const float* bv = (const float*)d_in[6];
  float* out = (float*)d_out;

  const size_t MN = (size_t)16384 * 512;
  short* Xb = (short*)d_ws;       // MN
  short* Wb = Xb + MN;            // 3 * 262144
  short* Q = Wb + 786432;         // MN (K follows contiguously)
  short* K = Q + MN;
  short* Vt = K + MN;             // [8][512][2048]
  short* P = Vt + MN;             // [8][2048][2048] unnormalized exp
  float* biasP = (float*)(P + (size_t)8 * 2048 * 2048);  // [3][512]
  float* l = biasP + 1536;        // [8*2048] row sums of exp

  prep<<<8968, 256, 0, stream>>>(feature, wq, wk, wv, bq, bk, bv, Xb, Wb, biasP, l);

  gemm_qkv256<<<dim3(2, 64, 3), 512, 0, stream>>>(Xb, Wb, biasP, Q, Vt);
  gemm_qk8<<<dim3(8, 8, 8), 512, 0, stream>>>(Q, K, P, l);

  const float iscl = 0.044194173824159216f;  // 1/sqrt(512)
  gemm_pv8<<<dim3(4, 8, 8), 512, 0, stream>>>(P, Vt, l, feature, out, iscl);
}

// Round 8
// 229.020 us; speedup vs baseline: 1.2555x; 1.0060x over previous
//
#include <hip/hip_runtime.h>
#include <cstdint>
#include <cstddef>

// B=8, N=2048, C=512
// out = feature + softmax(Q K^T) @ V / sqrt(C),  Q = X Wq^T + bq etc.
// R18: qk8/qkv256 4-phase -> 2-phase merge (32 MFMA/phase), keeping R12's
//      verified counted-vmcnt pipeline topology EXACTLY: same GLDS slot
//      schedule (pha stages T(kt+1).A1; phb stages T(kt+2).{A0,B0,B1}),
//      same single VMW(6)/K-tile, same WAR windows (re-enumerated), same
//      per-acc MFMA order (bit-identical numerics). Rationale: pv8 (the
//      same merged topology, fastest at 688 TF) shows phase overhead is
//      ~fixed per phase -> halving phases/K-tile raises MFMA duty.
// pv8 / prep verbatim from R12/R17.

typedef __bf16 bf16x8 __attribute__((ext_vector_type(8)));
typedef float f32x4 __attribute__((ext_vector_type(4)));
typedef short short4v __attribute__((ext_vector_type(4)));

__device__ __forceinline__ short f2b(float f) {
  union { float f; unsigned u; } u; u.f = f;
  unsigned r = (u.u + 0x7fffu + ((u.u >> 16) & 1u)) >> 16;  // RNE
  return (short)r;
}

#define GLDS(gptr, lptr) \
  __builtin_amdgcn_global_load_lds( \
      (const __attribute__((address_space(1))) unsigned int*)(const void*)(gptr), \
      (__attribute__((address_space(3))) unsigned int*)(void*)(lptr), 16, 0, 0)

// asm fragment load: invisible to SIInsertWaitcnts -> no auto vmcnt drain.
// Completion is ONLY guaranteed by the explicit lgkmcnt(0) below.
__device__ __forceinline__ bf16x8 ldfrag_a(const short* buf, int row, int kq) {
  const short* p = buf + row * 64 + ((kq ^ (row & 7)) * 8);
  bf16x8 r;
  asm volatile("ds_read_b128 %0, %1"
               : "=v"(r)
               : "v"((const __attribute__((address_space(3))) short*)(const void*)p));
  return r;
}

#define LGKM0_SB() do { \
    asm volatile("s_waitcnt lgkmcnt(0)" ::: "memory"); \
    __builtin_amdgcn_sched_barrier(0); } while (0)
#define VMW(n) asm volatile("s_waitcnt vmcnt(" #n ")" ::: "memory")
#define SBAR() __builtin_amdgcn_s_barrier()
#define PRIO1() __builtin_amdgcn_s_setprio(1)
#define PRIO0() __builtin_amdgcn_s_setprio(0)

__device__ __forceinline__ void ldA4(bf16x8 (&a)[4][2], const short* buf, int rb, int l4) {
#pragma unroll
  for (int j = 0; j < 4; ++j)
#pragma unroll
    for (int kk = 0; kk < 2; ++kk) a[j][kk] = ldfrag_a(buf, rb + j * 16, kk * 4 + l4);
}
__device__ __forceinline__ void ld2(bf16x8 (&b)[2][2], const short* buf, int rb, int l4) {
#pragma unroll
  for (int n = 0; n < 2; ++n)
#pragma unroll
    for (int kk = 0; kk < 2; ++kk) b[n][kk] = ldfrag_a(buf, rb + n * 16, kk * 4 + l4);
}
// kk-outer: dependent same-acc MFMAs are 8 apart; per-acc k-order unchanged.
__device__ __forceinline__ void mm42(f32x4 (&acc)[8][4], const bf16x8 (&a)[4][2],
                                     const bf16x8 (&b)[2][2], int io, int no) {
#pragma unroll
  for (int kk = 0; kk < 2; ++kk)
#pragma unroll
    for (int j = 0; j < 4; ++j)
#pragma unroll
      for (int n = 0; n < 2; ++n)
        acc[io + j][no + n] = __builtin_amdgcn_mfma_f32_16x16x32_bf16(
            a[j][kk], b[n][kk], acc[io + j][no + n], 0, 0, 0);
}
__device__ __forceinline__ void mm22(f32x4 (&acc)[4][4], const bf16x8 (&a)[2][2],
                                     const bf16x8 (&b)[2][2], int io, int no) {
#pragma unroll
  for (int kk = 0; kk < 2; ++kk)
#pragma unroll
    for (int j = 0; j < 2; ++j)
#pragma unroll
      for (int n = 0; n < 2; ++n)
        acc[io + j][no + n] = __builtin_amdgcn_mfma_f32_16x16x32_bf16(
            a[j][kk], b[n][kk], acc[io + j][no + n], 0, 0, 0);
}

// ---------------- merged prep: feature->bf16, weights->bf16, bias pack, l=0 ----------------
__global__ __launch_bounds__(256) void prep(const float* __restrict__ f,
                                            const float* __restrict__ w0,
                                            const float* __restrict__ w1,
                                            const float* __restrict__ w2,
                                            const float* __restrict__ b0,
                                            const float* __restrict__ b1,
                                            const float* __restrict__ b2,
                                            short* __restrict__ Xb, short* __restrict__ Wb,
                                            float* __restrict__ biasP, float* __restrict__ l) {
  const int bid = blockIdx.x;
  const int t = threadIdx.x;
  if (bid < 8192) {                       // feature: 2097152 float4
    int i = bid * 256 + t;
    float4 v = ((const float4*)f)[i];
    short4v o = { f2b(v.x), f2b(v.y), f2b(v.z), f2b(v.w) };
    *(short4v*)(Xb + (size_t)i * 4) = o;
  } else if (bid < 8960) {                // weights: 196608 float4
    int i = (bid - 8192) * 256 + t;
    const float* src = (i < 65536) ? w0 : (i < 131072) ? w1 : w2;
    float4 v = ((const float4*)src)[i & 65535];
    short4v o = { f2b(v.x), f2b(v.y), f2b(v.z), f2b(v.w) };
    *(short4v*)(Wb + (size_t)i * 4) = o;
  } else {                                // 8 blocks: l zero (16384 f32) + bias (1536)
    int i = (bid - 8960) * 256 + t;       // 0..2047
    float4 z = { 0.f, 0.f, 0.f, 0.f };
    ((float4*)l)[i * 2] = z;
    ((float4*)l)[i * 2 + 1] = z;
    if (i < 1536) {
      const float* s = (i < 512) ? b0 : (i < 1024) ? b1 : b2;
      biasP[i] = s[i & 511];
    }
  }
}

// ---------------- fused QKV projection: 256x256 tile, 2-phase/K-tile pipelined ----------
// z<2: A = W rows (output dim n), B = X rows (tokens m). C-row = n (quad-contig).
// z==2: A = X rows (tokens), B = W rows (d).        C-row = m -> Vt[d][token].
// pha: A0 x {B0,B1} (32 MFMA); stages T(kt+1).A1.
// phb: A1 x {B1,B0} (32 MFMA); stages T(kt+2).{A0,B0,B1}; VMW(6) = ALL T(kt+1).
__global__ __launch_bounds__(512, 2) void gemm_qkv256(const short* __restrict__ X,
                                                      const short* __restrict__ Wall,
                                                      const float* __restrict__ biasP,
                                                      short* __restrict__ Out,
                                                      short* __restrict__ VtOut) {
  __shared__ __align__(16) short As[2][16384];  // A rows 256x64 per buffer
  __shared__ __align__(16) short Bs[2][16384];  // B rows
  // XCD remap: 384 blocks (384 % 8 == 0 -> bijective).
  const int id = blockIdx.x + blockIdx.y * 2 + blockIdx.z * 128;
  const int swz = (id & 7) * 48 + (id >> 3);
  const int z = swz >> 7;               // 0..2
  const int rem = swz & 127;
  const int m0 = (rem >> 1) * 256;      // token rows
  const int n0 = (rem & 1) * 256;       // output dim
  const short* __restrict__ Wm = Wall + (size_t)z * 262144 + (size_t)n0 * 512;
  const short* __restrict__ Xm = X + (size_t)m0 * 512;
  const short* __restrict__ Ag = (z < 2) ? Wm : Xm;
  const short* __restrict__ Bg = (z < 2) ? Xm : Wm;
  const int t = threadIdx.x;
  const int lane = t & 63, w = t >> 6;
  const int aw = (w >> 2) * 64, bw = (w & 3) * 32;
  const int fr = lane & 15, l4 = lane >> 4;
  const int r0 = t >> 3;
  const int kswz = ((t & 7) ^ (r0 & 7)) * 8;  // pre-swizzled global source chunk
  const short* pA = Ag + (size_t)r0 * 512 + kswz;
  const short* pB = Bg + (size_t)r0 * 512 + kswz;

#define QV_STG_A(buf, h, kt) do { \
    GLDS(pA + (size_t)((h) * 128) * 512 + (kt) * 64, &As[(buf)][(h) * 8192 + t * 8]); \
    GLDS(pA + (size_t)((h) * 128 + 64) * 512 + (kt) * 64, &As[(buf)][(h) * 8192 + 4096 + t * 8]); \
  } while (0)
#define QV_STG_B(buf, h, kt) do { \
    GLDS(pB + (size_t)((h) * 128) * 512 + (kt) * 64, &Bs[(buf)][(h) * 8192 + t * 8]); \
    GLDS(pB + (size_t)((h) * 128 + 64) * 512 + (kt) * 64, &Bs[(buf)][(h) * 8192 + 4096 + t * 8]); \
  } while (0)

  f32x4 acc[8][4] = {};

  // prologue: T0.{A0,B0,B1,A1}, T1.{A0,B0,B1} = 14 loads; wait ALL of T0.
  QV_STG_A(0, 0, 0); QV_STG_B(0, 0, 0); QV_STG_B(0, 1, 0); QV_STG_A(0, 1, 0);
  QV_STG_A(1, 0, 1); QV_STG_B(1, 0, 1); QV_STG_B(1, 1, 1);
  VMW(6);
  SBAR();

  bf16x8 af[4][2], b0[2][2], b1[2][2];
  for (int kt = 0; kt < 6; ++kt) {
    const int c = kt & 1;
    const short* Ac = &As[c][0];
    const short* Bc = &Bs[c][0];
    // pha: A0 x {B0,B1}
    ldA4(af, Ac, aw + fr, l4); ld2(b0, Bc, bw + fr, l4); ld2(b1, Bc, 128 + bw + fr, l4);
    QV_STG_A(c ^ 1, 1, kt + 1);
    SBAR(); LGKM0_SB(); PRIO1();
    mm42(acc, af, b0, 0, 0); mm42(acc, af, b1, 0, 2);
    PRIO0(); SBAR();
    // phb: A1 x {B1,B0}; stage T(kt+2); single wait for ALL T(kt+1).
    ldA4(af, Ac, 128 + aw + fr, l4);
    QV_STG_A(c, 0, kt + 2); QV_STG_B(c, 0, kt + 2); QV_STG_B(c, 1, kt + 2);
    VMW(6);
    SBAR(); LGKM0_SB(); PRIO1();
    mm42(acc, af, b1, 4, 2); mm42(acc, af, b0, 4, 0);
    PRIO0(); SBAR();
  }
  {  // kt = 6 (buf 0): only T7.A1 left; phb waits ALL of T7 -> vmcnt(0).
    const short *Ac = &As[0][0], *Bc = &Bs[0][0];
    ldA4(af, Ac, aw + fr, l4); ld2(b0, Bc, bw + fr, l4); ld2(b1, Bc, 128 + bw + fr, l4);
    QV_STG_A(1, 1, 7);
    SBAR(); LGKM0_SB(); PRIO1();
    mm42(acc, af, b0, 0, 0); mm42(acc, af, b1, 0, 2);
    PRIO0(); SBAR();
    ldA4(af, Ac, 128 + aw + fr, l4);
    VMW(0);
    SBAR(); LGKM0_SB(); PRIO1();
    mm42(acc, af, b1, 4, 2); mm42(acc, af, b0, 4, 0);
    PRIO0(); SBAR();
  }
  {  // kt = 7 (buf 1): no staging, no vmem waits, no barriers needed.
    const short *Ac = &As[1][0], *Bc = &Bs[1][0];
    ldA4(af, Ac, aw + fr, l4); ld2(b0, Bc, bw + fr, l4); ld2(b1, Bc, 128 + bw + fr, l4);
    LGKM0_SB(); PRIO1();
    mm42(acc, af, b0, 0, 0); mm42(acc, af, b1, 0, 2);
    PRIO0();
    ldA4(af, Ac, 128 + aw + fr, l4);
    LGKM0_SB(); PRIO1();
    mm42(acc, af, b1, 4, 2); mm42(acc, af, b0, 4, 0);
    PRIO0();
  }
#undef QV_STG_A
#undef QV_STG_B

  if (z < 2) {
    // C-row = n (quad-contig), C-col = m.
#pragma unroll
    for (int i = 0; i < 8; ++i) {
      const int nb = n0 + aw + (i & 3) * 16 + (i >> 2) * 128 + l4 * 4;
      float4 bs = *(const float4*)(biasP + z * 512 + nb);
#pragma unroll
      for (int n = 0; n < 4; ++n) {
        const int m = m0 + bw + (n & 1) * 16 + (n >> 1) * 128 + fr;
        short4v o = { f2b(acc[i][n][0] + bs.x), f2b(acc[i][n][1] + bs.y),
                      f2b(acc[i][n][2] + bs.z), f2b(acc[i][n][3] + bs.w) };
        *(short4v*)(Out + (size_t)z * 8388608 + (size_t)m * 512 + nb) = o;
      }
    }
  } else {
    // C-row = m (quad-contig), C-col = d -> Vt[batch][d][token].
    const int zB = m0 >> 11;
    const int mb = m0 & 2047;
#pragma unroll
    for (int n = 0; n < 4; ++n) {
      const int d = n0 + bw + (n & 1) * 16 + (n >> 1) * 128 + fr;
      const float bd = biasP[1024 + d];
#pragma unroll
      for (int i = 0; i < 8; ++i) {
        const int mloc = mb + aw + (i & 3) * 16 + (i >> 2) * 128 + l4 * 4;
        short4v o = { f2b(acc[i][n][0] + bd), f2b(acc[i][n][1] + bd),
                      f2b(acc[i][n][2] + bd), f2b(acc[i][n][3] + bd) };
        *(short4v*)(VtOut + (size_t)zB * 1048576 + (size_t)d * 2048 + mloc) = o;
      }
    }
  }
}

// ---------------- QK^T: 256x256 tile, 2-phase/K-tile pipelined, exp epilogue ----------------
// A = K rows (keys), B = Q rows (queries). 8 waves 2(A)x4(B), per-wave 128x64.
// pha: A0 x {B0,B1}; stages T(kt+1).A1.
// phb: A1 x {B1,B0}; stages T(kt+2).{A0,B0,B1}; VMW(6) = ALL T(kt+1).
// FIFO: prologue 14, VMW(6)=T0; steady 8->14->VMW(6)=T(kt+1); kt=6 VMW(0);
// kt=7 barrier-free. WAR: every slot overwrite >=1 barrier after readers' lgkm0.
__global__ __launch_bounds__(512, 2) void gemm_qk8(const short* __restrict__ Q,
                                                   const short* __restrict__ Kb,
                                                   short* __restrict__ P,
                                                   float* __restrict__ l) {
  __shared__ __align__(16) short As[2][16384];  // keys   256x64 per buffer
  __shared__ __align__(16) short Bs[2][16384];  // queries
  // XCD remap: dispatch id -> one batch z per XCD (Q_z+K_z = 4MB = one L2).
  const int id = blockIdx.x + blockIdx.y * 8 + blockIdx.z * 64;
  const int swz = (id & 7) * 64 + (id >> 3);
  const int z = swz >> 6;
  const int m0 = ((swz >> 3) & 7) * 256;  // keys
  const int n0 = (swz & 7) * 256;         // queries
  const short* __restrict__ A = Kb + (size_t)z * 1048576;
  const short* __restrict__ B = Q + (size_t)z * 1048576;
  const int t = threadIdx.x;
  const int lane = t & 63, w = t >> 6;
  const int aw = (w >> 2) * 64, bw = (w & 3) * 32;
  const int fr = lane & 15, l4 = lane >> 4;
  const int r0 = t >> 3;
  const int kswz = ((t & 7) ^ (r0 & 7)) * 8;  // pre-swizzled global source chunk
  const short* pA = A + (size_t)(m0 + r0) * 512 + kswz;
  const short* pB = B + (size_t)(n0 + r0) * 512 + kswz;

#define QK_STG_A(buf, h, kt) do { \
    GLDS(pA + (size_t)((h) * 128) * 512 + (kt) * 64, &As[(buf)][(h) * 8192 + t * 8]); \
    GLDS(pA + (size_t)((h) * 128 + 64) * 512 + (kt) * 64, &As[(buf)][(h) * 8192 + 4096 + t * 8]); \
  } while (0)
#define QK_STG_B(buf, h, kt) do { \
    GLDS(pB + (size_t)((h) * 128) * 512 + (kt) * 64, &Bs[(buf)][(h) * 8192 + t * 8]); \
    GLDS(pB + (size_t)((h) * 128 + 64) * 512 + (kt) * 64, &Bs[(buf)][(h) * 8192 + 4096 + t * 8]); \
  } while (0)

  f32x4 acc[8][4] = {};

  // prologue: T0.{A0,B0,B1,A1}, T1.{A0,B0,B1} = 14 loads; wait ALL of T0.
  QK_STG_A(0, 0, 0); QK_STG_B(0, 0, 0); QK_STG_B(0, 1, 0); QK_STG_A(0, 1, 0);
  QK_STG_A(1, 0, 1); QK_STG_B(1, 0, 1); QK_STG_B(1, 1, 1);
  VMW(6);
  SBAR();

  bf16x8 af[4][2], b0[2][2], b1[2][2];
  for (int kt = 0; kt < 6; ++kt) {
    const int c = kt & 1;
    const short* Ac = &As[c][0];
    const short* Bc = &Bs[c][0];
    // pha: A0 x {B0,B1}
    ldA4(af, Ac, aw + fr, l4); ld2(b0, Bc, bw + fr, l4); ld2(b1, Bc, 128 + bw + fr, l4);
    QK_STG_A(c ^ 1, 1, kt + 1);
    SBAR(); LGKM0_SB(); PRIO1();
    mm42(acc, af, b0, 0, 0); mm42(acc, af, b1, 0, 2);
    PRIO0(); SBAR();
    // phb: A1 x {B1,B0}; stage T(kt+2); single wait for ALL T(kt+1).
    ldA4(af, Ac, 128 + aw + fr, l4);
    QK_STG_A(c, 0, kt + 2); QK_STG_B(c, 0, kt + 2); QK_STG_B(c, 1, kt + 2);
    VMW(6);
    SBAR(); LGKM0_SB(); PRIO1();
    mm42(acc, af, b1, 4, 2); mm42(acc, af, b0, 4, 0);
    PRIO0(); SBAR();
  }
  {  // kt = 6 (buf 0): only T7.A1 left; phb waits ALL of T7 -> vmcnt(0).
    const short *Ac = &As[0][0], *Bc = &Bs[0][0];
    ldA4(af, Ac, aw + fr, l4); ld2(b0, Bc, bw + fr, l4); ld2(b1, Bc, 128 + bw + fr, l4);
    QK_STG_A(1, 1, 7);
    SBAR(); LGKM0_SB(); PRIO1();
    mm42(acc, af, b0, 0, 0); mm42(acc, af, b1, 0, 2);
    PRIO0(); SBAR();
    ldA4(af, Ac, 128 + aw + fr, l4);
    VMW(0);
    SBAR(); LGKM0_SB(); PRIO1();
    mm42(acc, af, b1, 4, 2); mm42(acc, af, b0, 4, 0);
    PRIO0(); SBAR();
  }
  {  // kt = 7 (buf 1): no staging, no vmem waits, no barriers needed.
    const short *Ac = &As[1][0], *Bc = &Bs[1][0];
    ldA4(af, Ac, aw + fr, l4); ld2(b0, Bc, bw + fr, l4); ld2(b1, Bc, 128 + bw + fr, l4);
    LGKM0_SB(); PRIO1();
    mm42(acc, af, b0, 0, 0); mm42(acc, af, b1, 0, 2);
    PRIO0();
    ldA4(af, Ac, 128 + aw + fr, l4);
    LGKM0_SB(); PRIO1();
    mm42(acc, af, b1, 4, 2); mm42(acc, af, b0, 4, 0);
    PRIO0();
  }
#undef QK_STG_A
#undef QK_STG_B

  // epilogue: e = exp(score), store bf16 P[query][key], row-sum atomics.
  const float LOG2E = 1.4426950408889634f;
  float rs[4] = { 0.f, 0.f, 0.f, 0.f };
#pragma unroll
  for (int i = 0; i < 8; ++i) {
    const int key = m0 + aw + (i & 3) * 16 + (i >> 2) * 128 + l4 * 4;
#pragma unroll
    for (int n = 0; n < 4; ++n) {
      const int q = n0 + bw + (n & 1) * 16 + (n >> 1) * 128 + fr;
      short4v o;
      float part = 0.f;
#pragma unroll
      for (int r = 0; r < 4; ++r) {
        float e = exp2f(acc[i][n][r] * LOG2E);
        o[r] = f2b(e);
        part += e;
      }
      *(short4v*)(P + (size_t)z * 4194304 + (size_t)q * 2048 + key) = o;
      rs[n] += part;
    }
  }
#pragma unroll
  for (int n = 0; n < 4; ++n) {
    rs[n] += __shfl_xor(rs[n], 16);
    rs[n] += __shfl_xor(rs[n], 32);
  }
  if (l4 == 0) {
#pragma unroll
    for (int n = 0; n < 4; ++n)
      atomicAdd(&l[z * 2048 + n0 + bw + (n & 1) * 16 + (n >> 1) * 128 + fr], rs[n]);
  }
}

// ---------------- PV: 128(d) x 256(q) tile, 2-phase/K-tile pipelined (R12 verbatim) --------
__global__ __launch_bounds__(512, 2) void gemm_pv8(const short* __restrict__ Pm,
                                                   const short* __restrict__ Vt,
                                                   const float* __restrict__ l,
                                                   const float* __restrict__ resid,
                                                   float* __restrict__ out, float scale) {
  __shared__ __align__(16) short As[2][8192];   // Vt rows: 128x64
  __shared__ __align__(16) short Bs[2][16384];  // P rows: 256x64
  // XCD remap: one batch z per XCD -> all 32 z-blocks co-resident, P rows
  // fetched once into that XCD's L2 and read by its 4 d-tiles.
  const int id = blockIdx.x + blockIdx.y * 4 + blockIdx.z * 32;
  const int swz = (id & 7) * 32 + (id >> 3);
  const int z = swz >> 5;
  const int d0 = (swz & 3) * 128;
  const int n0 = ((swz >> 2) & 7) * 256;
  const short* __restrict__ A = Vt + (size_t)z * 1048576;  // [512][2048]
  const short* __restrict__ B = Pm + (size_t)z * 4194304;  // [2048][2048]
  const int t = threadIdx.x;
  const int lane = t & 63, w = t >> 6;
  const int aw = (w >> 2) * 32, bw = (w & 3) * 32;
  const int fr = lane & 15, l4 = lane >> 4;
  const int r0 = t >> 3;
  const int kswz = ((t & 7) ^ (r0 & 7)) * 8;
  const short* pA = A + (size_t)(d0 + r0) * 2048 + kswz;
  const short* pB = B + (size_t)(n0 + r0) * 2048 + kswz;

#define PV_STG_A(buf, h, kt) \
    GLDS(pA + (size_t)((h) * 64) * 2048 + (kt) * 64, &As[(buf)][(h) * 4096 + t * 8])
#define PV_STG_B(buf, h, kt) do { \
    GLDS(pB + (size_t)((h) * 128) * 2048 + (kt) * 64, &Bs[(buf)][(h) * 8192 + t * 8]); \
    GLDS(pB + (size_t)((h) * 128 + 64) * 2048 + (kt) * 64, &Bs[(buf)][(h) * 8192 + 4096 + t * 8]); \
  } while (0)

  f32x4 acc[4][4] = {};

  // prologue: T0 (6 loads) + T1.{A0,B0,B1} (5) = 11; wait ALL of T0 -> vmcnt(5).
  PV_STG_A(0, 0, 0); PV_STG_B(0, 0, 0); PV_STG_B(0, 1, 0); PV_STG_A(0, 1, 0);
  PV_STG_A(1, 0, 1); PV_STG_B(1, 0, 1); PV_STG_B(1, 1, 1);
  VMW(5);
  SBAR();

  bf16x8 a[2][2], b0[2][2], b1[2][2];
  for (int kt = 0; kt < 30; ++kt) {
    const int c = kt & 1;
    const short* Ac = &As[c][0];
    const short* Bc = &Bs[c][0];
    // pha (A0 x {b0,b1})
    ld2(a, Ac, aw + fr, l4); ld2(b0, Bc, bw + fr, l4); ld2(b1, Bc, 128 + bw + fr, l4);
    PV_STG_A(c ^ 1, 1, kt + 1);
    SBAR(); LGKM0_SB(); PRIO1();
    mm22(acc, a, b0, 0, 0); mm22(acc, a, b1, 0, 2);
    PRIO0(); SBAR();
    // phb (A1 x {b1,b0}); stage T(kt+2); single wait for ALL T(kt+1).
    ld2(a, Ac, 64 + aw + fr, l4);
    PV_STG_A(c, 0, kt + 2);
    PV_STG_B(c, 0, kt + 2);
    PV_STG_B(c, 1, kt + 2);
    VMW(5);
    SBAR(); LGKM0_SB(); PRIO1();
    mm22(acc, a, b1, 2, 2); mm22(acc, a, b0, 2, 0);
    PRIO0(); SBAR();
  }
  {  // kt = 30 (buf 0): only T31.A1 left; phb waits ALL T31 -> vmcnt(0).
    const short *Ac = &As[0][0], *Bc = &Bs[0][0];
    ld2(a, Ac, aw + fr, l4); ld2(b0, Bc, bw + fr, l4); ld2(b1, Bc, 128 + bw + fr, l4);
    PV_STG_A(1, 1, 31);
    SBAR(); LGKM0_SB(); PRIO1();
    mm22(acc, a, b0, 0, 0); mm22(acc, a, b1, 0, 2);
    PRIO0(); SBAR();
    ld2(a, Ac, 64 + aw + fr, l4);
    VMW(0);
    SBAR(); LGKM0_SB(); PRIO1();
    mm22(acc, a, b1, 2, 2); mm22(acc, a, b0, 2, 0);
    PRIO0(); SBAR();
  }
  {  // kt = 31 (buf 1): no staging, no vmem waits.
    const short *Ac = &As[1][0], *Bc = &Bs[1][0];
    ld2(a, Ac, aw + fr, l4); ld2(b0, Bc, bw + fr, l4); ld2(b1, Bc, 128 + bw + fr, l4);
    SBAR(); LGKM0_SB(); PRIO1();
    mm22(acc, a, b0, 0, 0); mm22(acc, a, b1, 0, 2);
    PRIO0(); SBAR();
    ld2(a, Ac, 64 + aw + fr, l4);
    LGKM0_SB(); PRIO1();
    mm22(acc, a, b1, 2, 2); mm22(acc, a, b0, 2, 0);
    PRIO0();
  }
#undef PV_STG_A
#undef PV_STG_B

  // epilogue: out = resid + acc * (scale / l[q])
  float linv[4];
#pragma unroll
  for (int n = 0; n < 4; ++n) {
    const int q = n0 + bw + (n & 1) * 16 + (n >> 1) * 128 + fr;
    linv[n] = scale / l[z * 2048 + q];
  }
#pragma unroll
  for (int n = 0; n < 4; ++n) {
    const int q = n0 + bw + (n & 1) * 16 + (n >> 1) * 128 + fr;
#pragma unroll
    for (int i = 0; i < 4; ++i) {
      const int d = d0 + aw + (i & 1) * 16 + (i >> 1) * 64 + l4 * 4;
      const size_t idx = (size_t)z * 1048576 + (size_t)q * 512 + d;
      float4 rv = *(const float4*)(resid + idx);
      float4 o = { rv.x + acc[i][n][0] * linv[n], rv.y + acc[i][n][1] * linv[n],
                   rv.z + acc[i][n][2] * linv[n], rv.w + acc[i][n][3] * linv[n] };
      *(float4*)(out + idx) = o;
    }
  }
}

extern "C" void kernel_launch(void* const* d_in, const int* in_sizes, int n_in,
                              void* d_out, int out_size, void* d_ws, size_t ws_size,
                              hipStream_t stream) {
  const float* feature = (const float*)d_in[0];
  const float* wq = (const float*)d_in[1];
  const float* bq = (const float*)d_in[2];
  const float* wk = (const float*)d_in[3];
  const float* bk = (const float*)d_in[4];
  const float* wv = (const float*)d_in[5];
  const float* bv = (const float*)d_in[6];
  float* out = (float*)d_out;

  const size_t MN = (size_t)16384 * 512;
  short* Xb = (short*)d_ws;       // MN
  short* Wb = Xb + MN;            // 3 * 262144
  short* Q = Wb + 786432;         // MN (K follows contiguously)
  short* K = Q + MN;
  short* Vt = K + MN;             // [8][512][2048]
  short* P = Vt + MN;             // [8][2048][2048] unnormalized exp
  float* biasP = (float*)(P + (size_t)8 * 2048 * 2048);  // [3][512]
  float* l = biasP + 1536;        // [8*2048] row sums of exp

  prep<<<8968, 256, 0, stream>>>(feature, wq, wk, wv, bq, bk, bv, Xb, Wb, biasP, l);

  gemm_qkv256<<<dim3(2, 64, 3), 512, 0, stream>>>(Xb, Wb, biasP, Q, Vt);
  gemm_qk8<<<dim3(8, 8, 8), 512, 0, stream>>>(Q, K, P, l);

  const float iscl = 0.044194173824159216f;  // 1/sqrt(512)
  gemm_pv8<<<dim3(4, 8, 8), 512, 0, stream>>>(P, Vt, l, feature, out, iscl);
}

// Round 9
// 222.922 us; speedup vs baseline: 1.2899x; 1.0274x over previous
//
#include <hip/hip_runtime.h>
#include <cstdint>
#include <cstddef>

// B=8, N=2048, C=512
// out = feature + softmax(Q K^T) @ V / sqrt(C),  Q = X Wq^T + bq etc.
// R19: grid-quantization fix for the QKV projection. R18's qkv256 ran 384
//      blocks on 256 CUs = 1 full + 1 half-empty round (2x T_block).
//      gemm_qkv2 = uniform 768 half-size blocks (3 full rounds), an exact
//      clone of pv8's verified 128(A) x 256(B) 2-phase skeleton (VMW(5)
//      steady / VMW(0) tail, NT=8, stride 512). Roles per z keep both
//      epilogues short4v-contiguous:
//        z<2: A=W rows (128 n), B=X rows (256 m)  -> C-row = n (quad)
//        z==2: A=X rows (128 tok), B=Wv (256 d)   -> C-row = tok -> Vt[d][tok]
// qk8 / pv8 / prep verbatim R18 (measured best total 229.0 µs).

typedef __bf16 bf16x8 __attribute__((ext_vector_type(8)));
typedef float f32x4 __attribute__((ext_vector_type(4)));
typedef short short4v __attribute__((ext_vector_type(4)));

__device__ __forceinline__ short f2b(float f) {
  union { float f; unsigned u; } u; u.f = f;
  unsigned r = (u.u + 0x7fffu + ((u.u >> 16) & 1u)) >> 16;  // RNE
  return (short)r;
}

#define GLDS(gptr, lptr) \
  __builtin_amdgcn_global_load_lds( \
      (const __attribute__((address_space(1))) unsigned int*)(const void*)(gptr), \
      (__attribute__((address_space(3))) unsigned int*)(void*)(lptr), 16, 0, 0)

// asm fragment load: invisible to SIInsertWaitcnts -> no auto vmcnt drain.
// Completion is ONLY guaranteed by the explicit lgkmcnt(0) below.
__device__ __forceinline__ bf16x8 ldfrag_a(const short* buf, int row, int kq) {
  const short* p = buf + row * 64 + ((kq ^ (row & 7)) * 8);
  bf16x8 r;
  asm volatile("ds_read_b128 %0, %1"
               : "=v"(r)
               : "v"((const __attribute__((address_space(3))) short*)(const void*)p));
  return r;
}

#define LGKM0_SB() do { \
    asm volatile("s_waitcnt lgkmcnt(0)" ::: "memory"); \
    __builtin_amdgcn_sched_barrier(0); } while (0)
#define VMW(n) asm volatile("s_waitcnt vmcnt(" #n ")" ::: "memory")
#define SBAR() __builtin_amdgcn_s_barrier()
#define PRIO1() __builtin_amdgcn_s_setprio(1)
#define PRIO0() __builtin_amdgcn_s_setprio(0)

__device__ __forceinline__ void ldA4(bf16x8 (&a)[4][2], const short* buf, int rb, int l4) {
#pragma unroll
  for (int j = 0; j < 4; ++j)
#pragma unroll
    for (int kk = 0; kk < 2; ++kk) a[j][kk] = ldfrag_a(buf, rb + j * 16, kk * 4 + l4);
}
__device__ __forceinline__ void ld2(bf16x8 (&b)[2][2], const short* buf, int rb, int l4) {
#pragma unroll
  for (int n = 0; n < 2; ++n)
#pragma unroll
    for (int kk = 0; kk < 2; ++kk) b[n][kk] = ldfrag_a(buf, rb + n * 16, kk * 4 + l4);
}
// kk-outer: dependent same-acc MFMAs are 8 apart; per-acc k-order unchanged.
__device__ __forceinline__ void mm42(f32x4 (&acc)[8][4], const bf16x8 (&a)[4][2],
                                     const bf16x8 (&b)[2][2], int io, int no) {
#pragma unroll
  for (int kk = 0; kk < 2; ++kk)
#pragma unroll
    for (int j = 0; j < 4; ++j)
#pragma unroll
      for (int n = 0; n < 2; ++n)
        acc[io + j][no + n] = __builtin_amdgcn_mfma_f32_16x16x32_bf16(
            a[j][kk], b[n][kk], acc[io + j][no + n], 0, 0, 0);
}
__device__ __forceinline__ void mm22(f32x4 (&acc)[4][4], const bf16x8 (&a)[2][2],
                                     const bf16x8 (&b)[2][2], int io, int no) {
#pragma unroll
  for (int kk = 0; kk < 2; ++kk)
#pragma unroll
    for (int j = 0; j < 2; ++j)
#pragma unroll
      for (int n = 0; n < 2; ++n)
        acc[io + j][no + n] = __builtin_amdgcn_mfma_f32_16x16x32_bf16(
            a[j][kk], b[n][kk], acc[io + j][no + n], 0, 0, 0);
}

// ---------------- merged prep: feature->bf16, weights->bf16, bias pack, l=0 ----------------
__global__ __launch_bounds__(256) void prep(const float* __restrict__ f,
                                            const float* __restrict__ w0,
                                            const float* __restrict__ w1,
                                            const float* __restrict__ w2,
                                            const float* __restrict__ b0,
                                            const float* __restrict__ b1,
                                            const float* __restrict__ b2,
                                            short* __restrict__ Xb, short* __restrict__ Wb,
                                            float* __restrict__ biasP, float* __restrict__ l) {
  const int bid = blockIdx.x;
  const int t = threadIdx.x;
  if (bid < 8192) {                       // feature: 2097152 float4
    int i = bid * 256 + t;
    float4 v = ((const float4*)f)[i];
    short4v o = { f2b(v.x), f2b(v.y), f2b(v.z), f2b(v.w) };
    *(short4v*)(Xb + (size_t)i * 4) = o;
  } else if (bid < 8960) {                // weights: 196608 float4
    int i = (bid - 8192) * 256 + t;
    const float* src = (i < 65536) ? w0 : (i < 131072) ? w1 : w2;
    float4 v = ((const float4*)src)[i & 65535];
    short4v o = { f2b(v.x), f2b(v.y), f2b(v.z), f2b(v.w) };
    *(short4v*)(Wb + (size_t)i * 4) = o;
  } else {                                // 8 blocks: l zero (16384 f32) + bias (1536)
    int i = (bid - 8960) * 256 + t;       // 0..2047
    float4 z = { 0.f, 0.f, 0.f, 0.f };
    ((float4*)l)[i * 2] = z;
    ((float4*)l)[i * 2 + 1] = z;
    if (i < 1536) {
      const float* s = (i < 512) ? b0 : (i < 1024) ? b1 : b2;
      biasP[i] = s[i & 511];
    }
  }
}

// ---------------- fused QKV projection: 128(A) x 256(B) tile, 2-phase, 768 blocks ----------
// pv8 skeleton, K=512 (NT=8). pha: A0 x {b0,b1}, stage T(kt+1).A1.
// phb: A1 x {b1,b0}, stage T(kt+2).{A0,B0,B1}, VMW(5) = ALL T(kt+1).
// Tails: kt=6 pha stages T7.A1, phb VMW(0); kt=7 no staging.
__global__ __launch_bounds__(512, 2) void gemm_qkv2(const short* __restrict__ X,
                                                    const short* __restrict__ Wall,
                                                    const float* __restrict__ biasP,
                                                    short* __restrict__ Out,
                                                    short* __restrict__ VtOut) {
  __shared__ __align__(16) short As[2][8192];   // A rows: 128x64
  __shared__ __align__(16) short Bs[2][16384];  // B rows: 256x64
  // XCD remap: 768 blocks, 768 % 8 == 0 -> bijective.
  const int id = blockIdx.x;
  const int swz = (id & 7) * 96 + (id >> 3);
  const int z = swz >> 8;               // 0..2
  const int r = swz & 255;
  // z<2: A = W rows [nt*128 .. +128), B = X rows [mtB*256 .. +256)
  // z=2: A = X rows [mtA*128 .. +128), B = Wv rows [dt*256 .. +256)
  const int nt = r & 3, mtB = r >> 2;      // z<2 decomposition (4 x 64)
  const int mtA = r >> 1, dt = r & 1;      // z=2 decomposition (128 x 2)
  const short* __restrict__ Ag = (z < 2)
      ? Wall + (size_t)z * 262144 + (size_t)nt * 128 * 512
      : X + (size_t)mtA * 128 * 512;
  const short* __restrict__ Bg = (z < 2)
      ? X + (size_t)mtB * 256 * 512
      : Wall + (size_t)2 * 262144 + (size_t)dt * 256 * 512;
  const int t = threadIdx.x;
  const int lane = t & 63, w = t >> 6;
  const int aw = (w >> 2) * 32, bw = (w & 3) * 32;
  const int fr = lane & 15, l4 = lane >> 4;
  const int r0 = t >> 3;
  const int kswz = ((t & 7) ^ (r0 & 7)) * 8;  // pre-swizzled global source chunk
  const short* pA = Ag + (size_t)r0 * 512 + kswz;
  const short* pB = Bg + (size_t)r0 * 512 + kswz;

#define QV_STG_A(buf, h, kt) \
    GLDS(pA + (size_t)((h) * 64) * 512 + (kt) * 64, &As[(buf)][(h) * 4096 + t * 8])
#define QV_STG_B(buf, h, kt) do { \
    GLDS(pB + (size_t)((h) * 128) * 512 + (kt) * 64, &Bs[(buf)][(h) * 8192 + t * 8]); \
    GLDS(pB + (size_t)((h) * 128 + 64) * 512 + (kt) * 64, &Bs[(buf)][(h) * 8192 + 4096 + t * 8]); \
  } while (0)

  f32x4 acc[4][4] = {};

  // prologue: T0 (6 loads) + T1.{A0,B0,B1} (5) = 11; wait ALL of T0 -> vmcnt(5).
  QV_STG_A(0, 0, 0); QV_STG_B(0, 0, 0); QV_STG_B(0, 1, 0); QV_STG_A(0, 1, 0);
  QV_STG_A(1, 0, 1); QV_STG_B(1, 0, 1); QV_STG_B(1, 1, 1);
  VMW(5);
  SBAR();

  bf16x8 a[2][2], b0[2][2], b1[2][2];
  for (int kt = 0; kt < 6; ++kt) {
    const int c = kt & 1;
    const short* Ac = &As[c][0];
    const short* Bc = &Bs[c][0];
    // pha (A0 x {b0,b1})
    ld2(a, Ac, aw + fr, l4); ld2(b0, Bc, bw + fr, l4); ld2(b1, Bc, 128 + bw + fr, l4);
    QV_STG_A(c ^ 1, 1, kt + 1);
    SBAR(); LGKM0_SB(); PRIO1();
    mm22(acc, a, b0, 0, 0); mm22(acc, a, b1, 0, 2);
    PRIO0(); SBAR();
    // phb (A1 x {b1,b0}); stage T(kt+2); single wait for ALL T(kt+1).
    ld2(a, Ac, 64 + aw + fr, l4);
    QV_STG_A(c, 0, kt + 2);
    QV_STG_B(c, 0, kt + 2);
    QV_STG_B(c, 1, kt + 2);
    VMW(5);
    SBAR(); LGKM0_SB(); PRIO1();
    mm22(acc, a, b1, 2, 2); mm22(acc, a, b0, 2, 0);
    PRIO0(); SBAR();
  }
  {  // kt = 6 (buf 0): only T7.A1 left; phb waits ALL T7 -> vmcnt(0).
    const short *Ac = &As[0][0], *Bc = &Bs[0][0];
    ld2(a, Ac, aw + fr, l4); ld2(b0, Bc, bw + fr, l4); ld2(b1, Bc, 128 + bw + fr, l4);
    QV_STG_A(1, 1, 7);
    SBAR(); LGKM0_SB(); PRIO1();
    mm22(acc, a, b0, 0, 0); mm22(acc, a, b1, 0, 2);
    PRIO0(); SBAR();
    ld2(a, Ac, 64 + aw + fr, l4);
    VMW(0);
    SBAR(); LGKM0_SB(); PRIO1();
    mm22(acc, a, b1, 2, 2); mm22(acc, a, b0, 2, 0);
    PRIO0(); SBAR();
  }
  {  // kt = 7 (buf 1): no staging, no vmem waits.
    const short *Ac = &As[1][0], *Bc = &Bs[1][0];
    ld2(a, Ac, aw + fr, l4); ld2(b0, Bc, bw + fr, l4); ld2(b1, Bc, 128 + bw + fr, l4);
    SBAR(); LGKM0_SB(); PRIO1();
    mm22(acc, a, b0, 0, 0); mm22(acc, a, b1, 0, 2);
    PRIO0(); SBAR();
    ld2(a, Ac, 64 + aw + fr, l4);
    LGKM0_SB(); PRIO1();
    mm22(acc, a, b1, 2, 2); mm22(acc, a, b0, 2, 0);
    PRIO0();
  }
#undef QV_STG_A
#undef QV_STG_B

  // epilogue. acc[i][n]: C-row = A-row (quad-contig) = aw + (i&1)*16 + (i>>1)*64 + l4*4;
  //           C-col = B-row = bw + (n&1)*16 + (n>>1)*128 + fr.
  if (z < 2) {
#pragma unroll
    for (int n = 0; n < 4; ++n) {
      const int m = mtB * 256 + bw + (n & 1) * 16 + (n >> 1) * 128 + fr;
#pragma unroll
      for (int i = 0; i < 4; ++i) {
        const int nb = nt * 128 + aw + (i & 1) * 16 + (i >> 1) * 64 + l4 * 4;
        float4 bs = *(const float4*)(biasP + z * 512 + nb);
        short4v o = { f2b(acc[i][n][0] + bs.x), f2b(acc[i][n][1] + bs.y),
                      f2b(acc[i][n][2] + bs.z), f2b(acc[i][n][3] + bs.w) };
        *(short4v*)(Out + (size_t)z * 8388608 + (size_t)m * 512 + nb) = o;
      }
    }
  } else {
    const int zB = mtA >> 4;
    const int mb = (mtA & 15) * 128;
#pragma unroll
    for (int n = 0; n < 4; ++n) {
      const int d = dt * 256 + bw + (n & 1) * 16 + (n >> 1) * 128 + fr;
      const float bd = biasP[1024 + d];
#pragma unroll
      for (int i = 0; i < 4; ++i) {
        const int mloc = mb + aw + (i & 1) * 16 + (i >> 1) * 64 + l4 * 4;
        short4v o = { f2b(acc[i][n][0] + bd), f2b(acc[i][n][1] + bd),
                      f2b(acc[i][n][2] + bd), f2b(acc[i][n][3] + bd) };
        *(short4v*)(VtOut + (size_t)zB * 1048576 + (size_t)d * 2048 + mloc) = o;
      }
    }
  }
}

// ---------------- QK^T: 256x256 tile, 2-phase/K-tile pipelined, exp epilogue (R18) ----------
__global__ __launch_bounds__(512, 2) void gemm_qk8(const short* __restrict__ Q,
                                                   const short* __restrict__ Kb,
                                                   short* __restrict__ P,
                                                   float* __restrict__ l) {
  __shared__ __align__(16) short As[2][16384];  // keys   256x64 per buffer
  __shared__ __align__(16) short Bs[2][16384];  // queries
  // XCD remap: dispatch id -> one batch z per XCD (Q_z+K_z = 4MB = one L2).
  const int id = blockIdx.x + blockIdx.y * 8 + blockIdx.z * 64;
  const int swz = (id & 7) * 64 + (id >> 3);
  const int z = swz >> 6;
  const int m0 = ((swz >> 3) & 7) * 256;  // keys
  const int n0 = (swz & 7) * 256;         // queries
  const short* __restrict__ A = Kb + (size_t)z * 1048576;
  const short* __restrict__ B = Q + (size_t)z * 1048576;
  const int t = threadIdx.x;
  const int lane = t & 63, w = t >> 6;
  const int aw = (w >> 2) * 64, bw = (w & 3) * 32;
  const int fr = lane & 15, l4 = lane >> 4;
  const int r0 = t >> 3;
  const int kswz = ((t & 7) ^ (r0 & 7)) * 8;  // pre-swizzled global source chunk
  const short* pA = A + (size_t)(m0 + r0) * 512 + kswz;
  const short* pB = B + (size_t)(n0 + r0) * 512 + kswz;

#define QK_STG_A(buf, h, kt) do { \
    GLDS(pA + (size_t)((h) * 128) * 512 + (kt) * 64, &As[(buf)][(h) * 8192 + t * 8]); \
    GLDS(pA + (size_t)((h) * 128 + 64) * 512 + (kt) * 64, &As[(buf)][(h) * 8192 + 4096 + t * 8]); \
  } while (0)
#define QK_STG_B(buf, h, kt) do { \
    GLDS(pB + (size_t)((h) * 128) * 512 + (kt) * 64, &Bs[(buf)][(h) * 8192 + t * 8]); \
    GLDS(pB + (size_t)((h) * 128 + 64) * 512 + (kt) * 64, &Bs[(buf)][(h) * 8192 + 4096 + t * 8]); \
  } while (0)

  f32x4 acc[8][4] = {};

  // prologue: T0.{A0,B0,B1,A1}, T1.{A0,B0,B1} = 14 loads; wait ALL of T0.
  QK_STG_A(0, 0, 0); QK_STG_B(0, 0, 0); QK_STG_B(0, 1, 0); QK_STG_A(0, 1, 0);
  QK_STG_A(1, 0, 1); QK_STG_B(1, 0, 1); QK_STG_B(1, 1, 1);
  VMW(6);
  SBAR();

  bf16x8 af[4][2], b0[2][2], b1[2][2];
  for (int kt = 0; kt < 6; ++kt) {
    const int c = kt & 1;
    const short* Ac = &As[c][0];
    const short* Bc = &Bs[c][0];
    // pha: A0 x {B0,B1}
    ldA4(af, Ac, aw + fr, l4); ld2(b0, Bc, bw + fr, l4); ld2(b1, Bc, 128 + bw + fr, l4);
    QK_STG_A(c ^ 1, 1, kt + 1);
    SBAR(); LGKM0_SB(); PRIO1();
    mm42(acc, af, b0, 0, 0); mm42(acc, af, b1, 0, 2);
    PRIO0(); SBAR();
    // phb: A1 x {B1,B0}; stage T(kt+2); single wait for ALL T(kt+1).
    ldA4(af, Ac, 128 + aw + fr, l4);
    QK_STG_A(c, 0, kt + 2); QK_STG_B(c, 0, kt + 2); QK_STG_B(c, 1, kt + 2);
    VMW(6);
    SBAR(); LGKM0_SB(); PRIO1();
    mm42(acc, af, b1, 4, 2); mm42(acc, af, b0, 4, 0);
    PRIO0(); SBAR();
  }
  {  // kt = 6 (buf 0): only T7.A1 left; phb waits ALL of T7 -> vmcnt(0).
    const short *Ac = &As[0][0], *Bc = &Bs[0][0];
    ldA4(af, Ac, aw + fr, l4); ld2(b0, Bc, bw + fr, l4); ld2(b1, Bc, 128 + bw + fr, l4);
    QK_STG_A(1, 1, 7);
    SBAR(); LGKM0_SB(); PRIO1();
    mm42(acc, af, b0, 0, 0); mm42(acc, af, b1, 0, 2);
    PRIO0(); SBAR();
    ldA4(af, Ac, 128 + aw + fr, l4);
    VMW(0);
    SBAR(); LGKM0_SB(); PRIO1();
    mm42(acc, af, b1, 4, 2); mm42(acc, af, b0, 4, 0);
    PRIO0(); SBAR();
  }
  {  // kt = 7 (buf 1): no staging, no vmem waits, no barriers needed.
    const short *Ac = &As[1][0], *Bc = &Bs[1][0];
    ldA4(af, Ac, aw + fr, l4); ld2(b0, Bc, bw + fr, l4); ld2(b1, Bc, 128 + bw + fr, l4);
    LGKM0_SB(); PRIO1();
    mm42(acc, af, b0, 0, 0); mm42(acc, af, b1, 0, 2);
    PRIO0();
    ldA4(af, Ac, 128 + aw + fr, l4);
    LGKM0_SB(); PRIO1();
    mm42(acc, af, b1, 4, 2); mm42(acc, af, b0, 4, 0);
    PRIO0();
  }
#undef QK_STG_A
#undef QK_STG_B

  // epilogue: e = exp(score), store bf16 P[query][key], row-sum atomics.
  const float LOG2E = 1.4426950408889634f;
  float rs[4] = { 0.f, 0.f, 0.f, 0.f };
#pragma unroll
  for (int i = 0; i < 8; ++i) {
    const int key = m0 + aw + (i & 3) * 16 + (i >> 2) * 128 + l4 * 4;
#pragma unroll
    for (int n = 0; n < 4; ++n) {
      const int q = n0 + bw + (n & 1) * 16 + (n >> 1) * 128 + fr;
      short4v o;
      float part = 0.f;
#pragma unroll
      for (int r = 0; r < 4; ++r) {
        float e = exp2f(acc[i][n][r] * LOG2E);
        o[r] = f2b(e);
        part += e;
      }
      *(short4v*)(P + (size_t)z * 4194304 + (size_t)q * 2048 + key) = o;
      rs[n] += part;
    }
  }
#pragma unroll
  for (int n = 0; n < 4; ++n) {
    rs[n] += __shfl_xor(rs[n], 16);
    rs[n] += __shfl_xor(rs[n], 32);
  }
  if (l4 == 0) {
#pragma unroll
    for (int n = 0; n < 4; ++n)
      atomicAdd(&l[z * 2048 + n0 + bw + (n & 1) * 16 + (n >> 1) * 128 + fr], rs[n]);
  }
}

// ---------------- PV: 128(d) x 256(q) tile, 2-phase/K-tile pipelined (R12 verbatim) --------
__global__ __launch_bounds__(512, 2) void gemm_pv8(const short* __restrict__ Pm,
                                                   const short* __restrict__ Vt,
                                                   const float* __restrict__ l,
                                                   const float* __restrict__ resid,
                                                   float* __restrict__ out, float scale) {
  __shared__ __align__(16) short As[2][8192];   // Vt rows: 128x64
  __shared__ __align__(16) short Bs[2][16384];  // P rows: 256x64
  // XCD remap: one batch z per XCD -> all 32 z-blocks co-resident, P rows
  // fetched once into that XCD's L2 and read by its 4 d-tiles.
  const int id = blockIdx.x + blockIdx.y * 4 + blockIdx.z * 32;
  const int swz = (id & 7) * 32 + (id >> 3);
  const int z = swz >> 5;
  const int d0 = (swz & 3) * 128;
  const int n0 = ((swz >> 2) & 7) * 256;
  const short* __restrict__ A = Vt + (size_t)z * 1048576;  // [512][2048]
  const short* __restrict__ B = Pm + (size_t)z * 4194304;  // [2048][2048]
  const int t = threadIdx.x;
  const int lane = t & 63, w = t >> 6;
  const int aw = (w >> 2) * 32, bw = (w & 3) * 32;
  const int fr = lane & 15, l4 = lane >> 4;
  const int r0 = t >> 3;
  const int kswz = ((t & 7) ^ (r0 & 7)) * 8;
  const short* pA = A + (size_t)(d0 + r0) * 2048 + kswz;
  const short* pB = B + (size_t)(n0 + r0) * 2048 + kswz;

#define PV_STG_A(buf, h, kt) \
    GLDS(pA + (size_t)((h) * 64) * 2048 + (kt) * 64, &As[(buf)][(h) * 4096 + t * 8])
#define PV_STG_B(buf, h, kt) do { \
    GLDS(pB + (size_t)((h) * 128) * 2048 + (kt) * 64, &Bs[(buf)][(h) * 8192 + t * 8]); \
    GLDS(pB + (size_t)((h) * 128 + 64) * 2048 + (kt) * 64, &Bs[(buf)][(h) * 8192 + 4096 + t * 8]); \
  } while (0)

  f32x4 acc[4][4] = {};

  // prologue: T0 (6 loads) + T1.{A0,B0,B1} (5) = 11; wait ALL of T0 -> vmcnt(5).
  PV_STG_A(0, 0, 0); PV_STG_B(0, 0, 0); PV_STG_B(0, 1, 0); PV_STG_A(0, 1, 0);
  PV_STG_A(1, 0, 1); PV_STG_B(1, 0, 1); PV_STG_B(1, 1, 1);
  VMW(5);
  SBAR();

  bf16x8 a[2][2], b0[2][2], b1[2][2];
  for (int kt = 0; kt < 30; ++kt) {
    const int c = kt & 1;
    const short* Ac = &As[c][0];
    const short* Bc = &Bs[c][0];
    // pha (A0 x {b0,b1})
    ld2(a, Ac, aw + fr, l4); ld2(b0, Bc, bw + fr, l4); ld2(b1, Bc, 128 + bw + fr, l4);
    PV_STG_A(c ^ 1, 1, kt + 1);
    SBAR(); LGKM0_SB(); PRIO1();
    mm22(acc, a, b0, 0, 0); mm22(acc, a, b1, 0, 2);
    PRIO0(); SBAR();
    // phb (A1 x {b1,b0}); stage T(kt+2); single wait for ALL T(kt+1).
    ld2(a, Ac, 64 + aw + fr, l4);
    PV_STG_A(c, 0, kt + 2);
    PV_STG_B(c, 0, kt + 2);
    PV_STG_B(c, 1, kt + 2);
    VMW(5);
    SBAR(); LGKM0_SB(); PRIO1();
    mm22(acc, a, b1, 2, 2); mm22(acc, a, b0, 2, 0);
    PRIO0(); SBAR();
  }
  {  // kt = 30 (buf 0): only T31.A1 left; phb waits ALL T31 -> vmcnt(0).
    const short *Ac = &As[0][0], *Bc = &Bs[0][0];
    ld2(a, Ac, aw + fr, l4); ld2(b0, Bc, bw + fr, l4); ld2(b1, Bc, 128 + bw + fr, l4);
    PV_STG_A(1, 1, 31);
    SBAR(); LGKM0_SB(); PRIO1();
    mm22(acc, a, b0, 0, 0); mm22(acc, a, b1, 0, 2);
    PRIO0(); SBAR();
    ld2(a, Ac, 64 + aw + fr, l4);
    VMW(0);
    SBAR(); LGKM0_SB(); PRIO1();
    mm22(acc, a, b1, 2, 2); mm22(acc, a, b0, 2, 0);
    PRIO0(); SBAR();
  }
  {  // kt = 31 (buf 1): no staging, no vmem waits.
    const short *Ac = &As[1][0], *Bc = &Bs[1][0];
    ld2(a, Ac, aw + fr, l4); ld2(b0, Bc, bw + fr, l4); ld2(b1, Bc, 128 + bw + fr, l4);
    SBAR(); LGKM0_SB(); PRIO1();
    mm22(acc, a, b0, 0, 0); mm22(acc, a, b1, 0, 2);
    PRIO0(); SBAR();
    ld2(a, Ac, 64 + aw + fr, l4);
    LGKM0_SB(); PRIO1();
    mm22(acc, a, b1, 2, 2); mm22(acc, a, b0, 2, 0);
    PRIO0();
  }
#undef PV_STG_A
#undef PV_STG_B

  // epilogue: out = resid + acc * (scale / l[q])
  float linv[4];
#pragma unroll
  for (int n = 0; n < 4; ++n) {
    const int q = n0 + bw + (n & 1) * 16 + (n >> 1) * 128 + fr;
    linv[n] = scale / l[z * 2048 + q];
  }
#pragma unroll
  for (int n = 0; n < 4; ++n) {
    const int q = n0 + bw + (n & 1) * 16 + (n >> 1) * 128 + fr;
#pragma unroll
    for (int i = 0; i < 4; ++i) {
      const int d = d0 + aw + (i & 1) * 16 + (i >> 1) * 64 + l4 * 4;
      const size_t idx = (size_t)z * 1048576 + (size_t)q * 512 + d;
      float4 rv = *(const float4*)(resid + idx);
      float4 o = { rv.x + acc[i][n][0] * linv[n], rv.y + acc[i][n][1] * linv[n],
                   rv.z + acc[i][n][2] * linv[n], rv.w + acc[i][n][3] * linv[n] };
      *(float4*)(out + idx) = o;
    }
  }
}

extern "C" void kernel_launch(void* const* d_in, const int* in_sizes, int n_in,
                              void* d_out, int out_size, void* d_ws, size_t ws_size,
                              hipStream_t stream) {
  const float* feature = (const float*)d_in[0];
  const float* wq = (const float*)d_in[1];
  const float* bq = (const float*)d_in[2];
  const float* wk = (const float*)d_in[3];
  const float* bk = (const float*)d_in[4];
  const float* wv = (const float*)d_in[5];
  const float* bv = (const float*)d_in[6];
  float* out = (float*)d_out;

  const size_t MN = (size_t)16384 * 512;
  short* Xb = (short*)d_ws;       // MN
  short* Wb = Xb + MN;            // 3 * 262144
  short* Q = Wb + 786432;         // MN (K follows contiguously)
  short* K = Q + MN;
  short* Vt = K + MN;             // [8][512][2048]
  short* P = Vt + MN;             // [8][2048][2048] unnormalized exp
  float* biasP = (float*)(P + (size_t)8 * 2048 * 2048);  // [3][512]
  float* l = biasP + 1536;        // [8*2048] row sums of exp

  prep<<<8968, 256, 0, stream>>>(feature, wq, wk, wv, bq, bk, bv, Xb, Wb, biasP, l);

  gemm_qkv2<<<768, 512, 0, stream>>>(Xb, Wb, biasP, Q, Vt);
  gemm_qk8<<<dim3(8, 8, 8), 512, 0, stream>>>(Q, K, P, l);

  const float iscl = 0.044194173824159216f;  // 1/sqrt(512)
  gemm_pv8<<<dim3(4, 8, 8), 512, 0, stream>>>(P, Vt, l, feature, out, iscl);
}